// Round 3
// baseline (687.351 us; speedup 1.0000x reference)
//
#include <hip/hip_runtime.h>
#include <cmath>
#include <cfloat>

#define HW_ 16384

__device__ __forceinline__ unsigned f2key(float f){
    unsigned u = __float_as_uint(f);
    return u ^ ((u & 0x80000000u) ? 0xFFFFFFFFu : 0x80000000u);
}
__device__ __forceinline__ float key2f(unsigned k){
    unsigned u = (k & 0x80000000u) ? (k ^ 0x80000000u) : ~k;
    return __uint_as_float(u);
}

#define SEL_CAP 1024

__device__ __forceinline__ void reduce_maxmin(unsigned locA, unsigned locB, int tid,
        unsigned* redA, unsigned* redB, unsigned* s_keyA, unsigned* s_keyB)
{
    #pragma unroll
    for (int o = 32; o > 0; o >>= 1){
        locA = max(locA, __shfl_down(locA, o));
        locB = min(locB, __shfl_down(locB, o));
    }
    if ((tid & 63) == 0){ redA[tid >> 6] = locA; redB[tid >> 6] = locB; }
    __syncthreads();
    if (tid == 0){
        unsigned a = redA[0], b = redB[0];
        for (int w = 1; w < 4; ++w){ a = max(a, redA[w]); b = min(b, redB[w]); }
        *s_keyA = a; *s_keyB = b;
    }
    __syncthreads();
}

// K1a: per (b,c) channel quantile threshold via dual-rank radix select.
// Channel keys kept in registers (64/thread) -> global read happens ONCE.
__global__ __launch_bounds__(256, 4) void k1a_thr(
    const float* __restrict__ x, float* __restrict__ throut)
{
    __shared__ unsigned hist[4096];
    __shared__ unsigned cand[SEL_CAP];
    __shared__ unsigned spart[256];
    __shared__ unsigned redA[4], redB[4];
    __shared__ unsigned s_cnt, s_dA, s_dB, s_cloA, s_cloB, s_keyA, s_keyB;

    const int tid = threadIdx.x;
    const unsigned bc = blockIdx.x;
    const float4* xp4 = (const float4*)(x + (size_t)bc * HW_);

    unsigned key[64];

    #pragma unroll
    for (int k = 0; k < 16; ++k) hist[tid + k * 256] = 0u;
    if (tid == 0) s_cnt = 0u;
    __syncthreads();

    // single global pass: load, convert, 12-bit histogram (bits 31..20)
    #pragma unroll 4
    for (int k = 0; k < 16; ++k){
        float4 v = xp4[tid + k * 256];
        key[4*k+0] = f2key(v.x);
        key[4*k+1] = f2key(v.y);
        key[4*k+2] = f2key(v.z);
        key[4*k+3] = f2key(v.w);
        atomicAdd(&hist[key[4*k+0] >> 20], 1u);
        atomicAdd(&hist[key[4*k+1] >> 20], 1u);
        atomicAdd(&hist[key[4*k+2] >> 20], 1u);
        atomicAdd(&hist[key[4*k+3] >> 20], 1u);
    }
    __syncthreads();

    unsigned rA = 15563u, rB = 15564u;     // ascending ranks (0-based)
    unsigned prefVal = 0u, prefMask = 0u;
    bool done = false;

    // ---- level 0: 12-bit ----
    {
        unsigned part = 0u;
        #pragma unroll
        for (int k = 0; k < 16; ++k) part += hist[tid * 16 + k];
        spart[tid] = part;
        __syncthreads();
        for (int off = 1; off < 256; off <<= 1){
            unsigned v = (tid >= off) ? spart[tid - off] : 0u;
            __syncthreads();
            spart[tid] += v;
            __syncthreads();
        }
        unsigned plo = (tid == 0) ? 0u : spart[tid - 1];
        unsigned phi = spart[tid];
        if (rA >= plo && rA < phi){
            unsigned c = plo;
            for (int k = 0; k < 16; ++k){
                unsigned hh = hist[tid * 16 + k];
                if (rA < c + hh){ s_dA = tid * 16 + k; s_cloA = c; break; }
                c += hh;
            }
        }
        if (rB >= plo && rB < phi){
            unsigned c = plo;
            for (int k = 0; k < 16; ++k){
                unsigned hh = hist[tid * 16 + k];
                if (rB < c + hh){ s_dB = tid * 16 + k; s_cloB = c; break; }
                c += hh;
            }
        }
        __syncthreads();
        unsigned dA = s_dA, dB = s_dB;
        if (dA != dB){
            unsigned locA = 0u, locB = 0xFFFFFFFFu;
            #pragma unroll
            for (int e = 0; e < 64; ++e){
                unsigned d = key[e] >> 20;
                if (d == dA) locA = max(locA, key[e]);
                if (d == dB) locB = min(locB, key[e]);
            }
            reduce_maxmin(locA, locB, tid, redA, redB, &s_keyA, &s_keyB);
            done = true;
        } else {
            prefVal = dA << 20; prefMask = 0xFFFu << 20;
            rA -= s_cloA; rB -= s_cloB;
            #pragma unroll
            for (int e = 0; e < 64; ++e){
                if ((key[e] >> 20) == dA){
                    unsigned id2 = atomicAdd(&s_cnt, 1u);
                    if (id2 < SEL_CAP) cand[id2] = key[e];
                }
            }
            __syncthreads();
        }
    }

    // ---- levels 1..3: 8,8,4 bits over candidate list (or registers) ----
    if (!done){
        unsigned nc = s_cnt;
        bool useCand = (nc <= SEL_CAP);
        const int shifts[3] = {12, 4, 0};
        const int bitsv[3]  = {8, 8, 4};
        for (int lvl = 0; lvl < 3 && !done; ++lvl){
            int shift = shifts[lvl];
            unsigned nb = 1u << bitsv[lvl];
            unsigned msk = nb - 1u;
            if (tid < (int)nb) hist[tid] = 0u;
            __syncthreads();
            if (useCand){
                for (unsigned i = tid; i < nc; i += 256){
                    unsigned k2 = cand[i];
                    if ((k2 & prefMask) == prefVal)
                        atomicAdd(&hist[(k2 >> shift) & msk], 1u);
                }
            } else {
                #pragma unroll
                for (int e = 0; e < 64; ++e){
                    if ((key[e] & prefMask) == prefVal)
                        atomicAdd(&hist[(key[e] >> shift) & msk], 1u);
                }
            }
            __syncthreads();
            spart[tid] = (tid < (int)nb) ? hist[tid] : 0u;
            __syncthreads();
            for (int off = 1; off < 256; off <<= 1){
                unsigned v = (tid >= off) ? spart[tid - off] : 0u;
                __syncthreads();
                spart[tid] += v;
                __syncthreads();
            }
            unsigned plo = (tid == 0) ? 0u : spart[tid - 1];
            unsigned phi = spart[tid];
            if (tid < (int)nb){
                if (rA >= plo && rA < phi){ s_dA = tid; s_cloA = plo; }
                if (rB >= plo && rB < phi){ s_dB = tid; s_cloB = plo; }
            }
            __syncthreads();
            unsigned dA = s_dA, dB = s_dB;
            if (dA != dB){
                unsigned mA = prefMask | (msk << shift);
                unsigned vAp = prefVal | (dA << shift);
                unsigned vBp = prefVal | (dB << shift);
                unsigned locA = 0u, locB = 0xFFFFFFFFu;
                if (useCand){
                    for (unsigned i = tid; i < nc; i += 256){
                        unsigned k2 = cand[i];
                        if ((k2 & mA) == vAp) locA = max(locA, k2);
                        if ((k2 & mA) == vBp) locB = min(locB, k2);
                    }
                } else {
                    #pragma unroll
                    for (int e = 0; e < 64; ++e){
                        if ((key[e] & mA) == vAp) locA = max(locA, key[e]);
                        if ((key[e] & mA) == vBp) locB = min(locB, key[e]);
                    }
                }
                reduce_maxmin(locA, locB, tid, redA, redB, &s_keyA, &s_keyB);
                done = true;
            } else {
                prefVal |= dA << shift;
                prefMask |= msk << shift;
                rA -= s_cloA; rB -= s_cloB;
                if (lvl == 2){
                    if (tid == 0){ s_keyA = prefVal; s_keyB = prefVal; }
                    done = true;
                }
                __syncthreads();
            }
        }
    }

    if (tid == 0){
        float vlo = key2f(s_keyA);
        float vhi = key2f(s_keyB);
        float idxq = 0.95f * 16383.0f;
        float frac = idxq - floorf(idxq);
        throut[bc] = vlo * (1.0f - frac) + vhi * frac;
    }
}

// K1b: tiled mask + pools, 16 output rows/block, fused passes.
// Pass1: load+mask+hmax3 (shuffles). Pass2: a1 + outp. Pass3: H5. Pass4: d1.
// LDS ~30.5KB -> 5 blocks/CU.
__global__ __launch_bounds__(256) void k1b_prop(
    const float* __restrict__ x, const float* __restrict__ thrbuf,
    float* __restrict__ outp, float* __restrict__ d1g, float g1)
{
    __shared__ __align__(16) float C0[21 * 128];
    __shared__ __align__(16) float A [21 * 128];   // reused as H5[19*64] in pass3
    __shared__ __align__(16) float A1[19 * 128];

    const int tid = threadIdx.x;
    const unsigned blk = blockIdx.x;
    const unsigned bc = blk >> 3;
    const int r0 = (int)(blk & 7u) * 16;

    const float thr = thrbuf[bc];
    const float4* xp4 = (const float4*)(x + (size_t)bc * HW_);

    // pass 1: 21 rows: load, mask -> C0; horizontal max3 via shuffles -> A
    #pragma unroll
    for (int p = 0; p < 3; ++p){
        int i = tid + p * 256;
        if (i < 21 * 32){
            int la = i >> 5, c4 = i & 31;
            int r = r0 - 3 + la;
            float4 c;
            if (r >= 0 && r < 128){
                float4 v = xp4[r * 32 + c4];
                c.x = (v.x >= thr) ? v.x : 0.0f;
                c.y = (v.y >= thr) ? v.y : 0.0f;
                c.z = (v.z >= thr) ? v.z : 0.0f;
                c.w = (v.w >= thr) ? v.w : 0.0f;
            } else {
                c.x = c.y = c.z = c.w = -FLT_MAX;
            }
            ((float4*)C0)[i] = c;
            float lf = __shfl_up(c.w, 1);
            float rt = __shfl_down(c.x, 1);
            if (c4 == 0)  lf = -FLT_MAX;
            if (c4 == 31) rt = -FLT_MAX;
            float4 a;
            a.x = fmaxf(fmaxf(lf,  c.x), c.y);
            a.y = fmaxf(fmaxf(c.x, c.y), c.z);
            a.z = fmaxf(fmaxf(c.y, c.z), c.w);
            a.w = fmaxf(fmaxf(c.z, c.w), rt);
            ((float4*)A)[i] = a;
        }
    }
    __syncthreads();

    // pass 2: vertical max3 * 0.99 -> A1 (19 rows); outp for the 16 output rows
    {
        float* op = outp + (size_t)bc * HW_;
        #pragma unroll
        for (int p = 0; p < 10; ++p){
            int i = tid + p * 256;
            if (i < 19 * 128){
                int la1 = i >> 7, j = i & 127;
                float m = fmaxf(fmaxf(A[la1 * 128 + j], A[(la1 + 1) * 128 + j]),
                                A[(la1 + 2) * 128 + j]);
                float a1 = 0.99f * m;
                A1[i] = a1;
                if (la1 >= 2 && la1 < 18){
                    float c0 = C0[(la1 + 1) * 128 + j];
                    op[(r0 + la1 - 2) * 128 + j] = fmaxf(c0, a1);
                }
            }
        }
    }
    __syncthreads();

    // pass 3: horizontal 5-tap at even centers over A1 -> H5 (alias of A)
    float* H5 = A;
    #pragma unroll
    for (int p = 0; p < 5; ++p){
        int i = tid + p * 256;
        if (i < 19 * 64){
            int lr = i >> 6, ci = i & 63;
            int c = 2 * ci;
            const float* row = A1 + lr * 128;
            float m = fmaxf(row[c], row[c + 1]);
            if (ci > 0)  m = fmaxf(m, fmaxf(row[c - 1], row[c - 2]));
            if (ci < 63) m = fmaxf(m, row[c + 2]);
            H5[i] = m;
        }
    }
    __syncthreads();

    // pass 4: vertical 5-tap stride-2 + scale -> d1 rows r0/2 .. r0/2+7
    {
        float* dp = d1g + (size_t)bc * 4096;
        #pragma unroll
        for (int p = 0; p < 2; ++p){
            int i = tid + p * 256;
            int li = i >> 6, j = i & 63;
            int lr = 2 * li;
            float m = fmaxf(fmaxf(H5[lr * 64 + j], H5[(lr + 1) * 64 + j]),
                     fmaxf(fmaxf(H5[(lr + 2) * 64 + j], H5[(lr + 3) * 64 + j]),
                           H5[(lr + 4) * 64 + j]));
            dp[(r0 / 2 + li) * 64 + j] = g1 * m;
        }
    }
}

// K2: 64x64 chain d2..d5, m64 = max(d1..d5), in-place over d1 buffer
__global__ __launch_bounds__(256) void k2_chain(
    float* __restrict__ dm, float g2, float g3, float g4, float g5)
{
    __shared__ __align__(16) float D[4096];
    __shared__ __align__(16) float T[4096];
    __shared__ __align__(16) float M[4096];
    const int tid = threadIdx.x;
    const unsigned bc = blockIdx.x;
    float* p = dm + (size_t)bc * 4096;
    const float4* p4 = (const float4*)p;
    #pragma unroll
    for (int k = 0; k < 4; ++k){
        float4 v = p4[tid + k * 256];
        ((float4*)D)[tid + k * 256] = v;
        ((float4*)M)[tid + k * 256] = v;
    }
    __syncthreads();
    const float gs[4] = {g2, g3, g4, g5};
    for (int it = 0; it < 4; ++it){
        float g = gs[it];
        #pragma unroll 4
        for (int k = 0; k < 16; ++k){
            int q = tid + k * 256;
            int j = q & 63;
            float m = D[q];
            if (j > 0)  m = fmaxf(m, D[q - 1]);
            if (j < 63) m = fmaxf(m, D[q + 1]);
            T[q] = m;
        }
        __syncthreads();
        #pragma unroll 4
        for (int k = 0; k < 16; ++k){
            int q = tid + k * 256;
            int r = q >> 6;
            float m = T[q];
            if (r > 0)  m = fmaxf(m, T[q - 64]);
            if (r < 63) m = fmaxf(m, T[q + 64]);
            float v = g * m;
            D[q] = v;
            M[q] = fmaxf(M[q], v);
        }
        __syncthreads();
    }
    #pragma unroll
    for (int k = 0; k < 4; ++k)
        ((float4*)p)[tid + k * 256] = ((float4*)M)[tid + k * 256];
}

// K3: fused  out' = max(outp, up(m64)) -> h = relu(W1 out'+b1) ->
//            R = sigmoid(W2 h + b2) -> y = x*R
// 2 px/thread (even col pair shares one m64 read). 512 blocks.
__global__ __launch_bounds__(256) void k3_mlp(
    const float* __restrict__ x, const float* __restrict__ outp,
    const float* __restrict__ m64,
    const float* __restrict__ w1, const float* __restrict__ b1,
    const float* __restrict__ w2, const float* __restrict__ b2,
    float* __restrict__ y)
{
    __shared__ __align__(16) float W1s[256 * 16];  // [c][m]
    __shared__ __align__(16) float W2s[256 * 16];  // [c][m]
    __shared__ float B1s[16];
    __shared__ float B2s[256];
    const int tid = threadIdx.x;
    const int blk = blockIdx.x;
    const int b = blk >> 5;
    const int t = blk & 31;

    for (int q = tid; q < 4096; q += 256){
        int c = q >> 4, m = q & 15;
        W1s[q] = w1[m * 256 + c];
        W2s[q] = w2[q];
    }
    if (tid < 16) B1s[tid] = b1[tid];
    B2s[tid] = b2[tid];
    __syncthreads();

    const int pix0 = t * 512 + tid * 2;
    const int mi = (pix0 >> 8) * 64 + ((pix0 & 127) >> 1);
    const size_t base = (size_t)b * 256 * HW_;
    const size_t mbase = (size_t)b * 256 * 4096;

    float h0[16], h1[16];
    #pragma unroll
    for (int m = 0; m < 16; ++m){ h0[m] = 0.0f; h1[m] = 0.0f; }

    #pragma unroll 4
    for (int c = 0; c < 256; ++c){
        float2 o2 = *(const float2*)&outp[base + (size_t)c * HW_ + pix0];
        float mo = m64[mbase + (size_t)c * 4096 + mi];
        float oa = fmaxf(o2.x, mo);
        float ob = fmaxf(o2.y, mo);
        const float4* wr = (const float4*)&W1s[c * 16];
        float4 a0 = wr[0], a1 = wr[1], a2 = wr[2], a3 = wr[3];
        h0[0]  = fmaf(a0.x, oa, h0[0]);  h1[0]  = fmaf(a0.x, ob, h1[0]);
        h0[1]  = fmaf(a0.y, oa, h0[1]);  h1[1]  = fmaf(a0.y, ob, h1[1]);
        h0[2]  = fmaf(a0.z, oa, h0[2]);  h1[2]  = fmaf(a0.z, ob, h1[2]);
        h0[3]  = fmaf(a0.w, oa, h0[3]);  h1[3]  = fmaf(a0.w, ob, h1[3]);
        h0[4]  = fmaf(a1.x, oa, h0[4]);  h1[4]  = fmaf(a1.x, ob, h1[4]);
        h0[5]  = fmaf(a1.y, oa, h0[5]);  h1[5]  = fmaf(a1.y, ob, h1[5]);
        h0[6]  = fmaf(a1.z, oa, h0[6]);  h1[6]  = fmaf(a1.z, ob, h1[6]);
        h0[7]  = fmaf(a1.w, oa, h0[7]);  h1[7]  = fmaf(a1.w, ob, h1[7]);
        h0[8]  = fmaf(a2.x, oa, h0[8]);  h1[8]  = fmaf(a2.x, ob, h1[8]);
        h0[9]  = fmaf(a2.y, oa, h0[9]);  h1[9]  = fmaf(a2.y, ob, h1[9]);
        h0[10] = fmaf(a2.z, oa, h0[10]); h1[10] = fmaf(a2.z, ob, h1[10]);
        h0[11] = fmaf(a2.w, oa, h0[11]); h1[11] = fmaf(a2.w, ob, h1[11]);
        h0[12] = fmaf(a3.x, oa, h0[12]); h1[12] = fmaf(a3.x, ob, h1[12]);
        h0[13] = fmaf(a3.y, oa, h0[13]); h1[13] = fmaf(a3.y, ob, h1[13]);
        h0[14] = fmaf(a3.z, oa, h0[14]); h1[14] = fmaf(a3.z, ob, h1[14]);
        h0[15] = fmaf(a3.w, oa, h0[15]); h1[15] = fmaf(a3.w, ob, h1[15]);
    }
    #pragma unroll
    for (int m = 0; m < 16; ++m){
        h0[m] = fmaxf(h0[m] + B1s[m], 0.0f);
        h1[m] = fmaxf(h1[m] + B1s[m], 0.0f);
    }

    #pragma unroll 4
    for (int c = 0; c < 256; ++c){
        const float4* wr = (const float4*)&W2s[c * 16];
        float4 a0 = wr[0], a1 = wr[1], a2 = wr[2], a3 = wr[3];
        float acc0 = B2s[c], acc1 = B2s[c];
        acc0 += a0.x * h0[0]  + a0.y * h0[1]  + a0.z * h0[2]  + a0.w * h0[3];
        acc1 += a0.x * h1[0]  + a0.y * h1[1]  + a0.z * h1[2]  + a0.w * h1[3];
        acc0 += a1.x * h0[4]  + a1.y * h0[5]  + a1.z * h0[6]  + a1.w * h0[7];
        acc1 += a1.x * h1[4]  + a1.y * h1[5]  + a1.z * h1[6]  + a1.w * h1[7];
        acc0 += a2.x * h0[8]  + a2.y * h0[9]  + a2.z * h0[10] + a2.w * h0[11];
        acc1 += a2.x * h1[8]  + a2.y * h1[9]  + a2.z * h1[10] + a2.w * h1[11];
        acc0 += a3.x * h0[12] + a3.y * h0[13] + a3.z * h0[14] + a3.w * h0[15];
        acc1 += a3.x * h1[12] + a3.y * h1[13] + a3.z * h1[14] + a3.w * h1[15];
        float R0 = 1.0f / (1.0f + __expf(-acc0));
        float R1 = 1.0f / (1.0f + __expf(-acc1));
        float2 xv = *(const float2*)&x[base + (size_t)c * HW_ + pix0];
        float2 yv; yv.x = xv.x * R0; yv.y = xv.y * R1;
        *(float2*)&y[base + (size_t)c * HW_ + pix0] = yv;
    }
}

extern "C" void kernel_launch(void* const* d_in, const int* in_sizes, int n_in,
                              void* d_out, int out_size, void* d_ws, size_t ws_size,
                              hipStream_t stream) {
    const float* x  = (const float*)d_in[0];
    const float* w1 = (const float*)d_in[1];
    const float* b1 = (const float*)d_in[2];
    const float* w2 = (const float*)d_in[3];
    const float* b2 = (const float*)d_in[4];
    float* y  = (float*)d_out;
    float* ws = (float*)d_ws;

    float* outp = ws;                          // 67108864 floats (268 MB)
    float* d1   = ws + 67108864;               // 16777216 floats (67 MB), reused as m64
    float* thrb = ws + 67108864 + 16777216;    // 4096 floats

    float g[6];
    for (int i = 0; i < 6; ++i) g[i] = (float)std::pow(0.99, (double)(1 << i));

    k1a_thr <<<4096, 256, 0, stream>>>(x, thrb);
    k1b_prop<<<32768, 256, 0, stream>>>(x, thrb, outp, d1, g[1]);
    k2_chain<<<4096, 256, 0, stream>>>(d1, g[2], g[3], g[4], g[5]);
    k3_mlp  <<<512, 256, 0, stream>>>(x, outp, d1, w1, b1, w2, b2, y);
}

// Round 4
// 549.034 us; speedup vs baseline: 1.2519x; 1.2519x over previous
//
#include <hip/hip_runtime.h>
#include <cmath>
#include <cfloat>

#define HW_ 16384

__device__ __forceinline__ unsigned f2key(float f){
    unsigned u = __float_as_uint(f);
    return u ^ ((u & 0x80000000u) ? 0xFFFFFFFFu : 0x80000000u);
}
__device__ __forceinline__ float key2f(unsigned k){
    unsigned u = (k & 0x80000000u) ? (k ^ 0x80000000u) : ~k;
    return __uint_as_float(u);
}
// bf16 storage helpers (RNE)
__device__ __forceinline__ unsigned short f2bf(float f){
    unsigned u = __float_as_uint(f);
    unsigned r = u + 0x7FFFu + ((u >> 16) & 1u);
    return (unsigned short)(r >> 16);
}
__device__ __forceinline__ float bf2f(unsigned short s){
    return __uint_as_float((unsigned)s << 16);
}

#define SEL_CAP 1024

__device__ __forceinline__ void reduce_maxmin(unsigned locA, unsigned locB, int tid,
        unsigned* redA, unsigned* redB, unsigned* s_keyA, unsigned* s_keyB)
{
    #pragma unroll
    for (int o = 32; o > 0; o >>= 1){
        locA = max(locA, __shfl_down(locA, o));
        locB = min(locB, __shfl_down(locB, o));
    }
    if ((tid & 63) == 0){ redA[tid >> 6] = locA; redB[tid >> 6] = locB; }
    __syncthreads();
    if (tid == 0){
        unsigned a = redA[0], b = redB[0];
        for (int w = 1; w < 4; ++w){ a = max(a, redA[w]); b = min(b, redB[w]); }
        *s_keyA = a; *s_keyB = b;
    }
    __syncthreads();
}

// K1a: per (b,c) channel quantile threshold via dual-rank radix select.
// Channel keys kept in registers (64/thread) -> global read happens ONCE.
__global__ __launch_bounds__(256, 4) void k1a_thr(
    const float* __restrict__ x, float* __restrict__ throut)
{
    __shared__ unsigned hist[4096];
    __shared__ unsigned cand[SEL_CAP];
    __shared__ unsigned spart[256];
    __shared__ unsigned redA[4], redB[4];
    __shared__ unsigned s_cnt, s_dA, s_dB, s_cloA, s_cloB, s_keyA, s_keyB;

    const int tid = threadIdx.x;
    const unsigned bc = blockIdx.x;
    const float4* xp4 = (const float4*)(x + (size_t)bc * HW_);

    unsigned key[64];

    #pragma unroll
    for (int k = 0; k < 16; ++k) hist[tid + k * 256] = 0u;
    if (tid == 0) s_cnt = 0u;
    __syncthreads();

    // single global pass: load, convert, 12-bit histogram (bits 31..20)
    #pragma unroll 4
    for (int k = 0; k < 16; ++k){
        float4 v = xp4[tid + k * 256];
        key[4*k+0] = f2key(v.x);
        key[4*k+1] = f2key(v.y);
        key[4*k+2] = f2key(v.z);
        key[4*k+3] = f2key(v.w);
        atomicAdd(&hist[key[4*k+0] >> 20], 1u);
        atomicAdd(&hist[key[4*k+1] >> 20], 1u);
        atomicAdd(&hist[key[4*k+2] >> 20], 1u);
        atomicAdd(&hist[key[4*k+3] >> 20], 1u);
    }
    __syncthreads();

    unsigned rA = 15563u, rB = 15564u;     // ascending ranks (0-based)
    unsigned prefVal = 0u, prefMask = 0u;
    bool done = false;

    // ---- level 0: 12-bit ----
    {
        unsigned part = 0u;
        #pragma unroll
        for (int k = 0; k < 16; ++k) part += hist[tid * 16 + k];
        spart[tid] = part;
        __syncthreads();
        for (int off = 1; off < 256; off <<= 1){
            unsigned v = (tid >= off) ? spart[tid - off] : 0u;
            __syncthreads();
            spart[tid] += v;
            __syncthreads();
        }
        unsigned plo = (tid == 0) ? 0u : spart[tid - 1];
        unsigned phi = spart[tid];
        if (rA >= plo && rA < phi){
            unsigned c = plo;
            for (int k = 0; k < 16; ++k){
                unsigned hh = hist[tid * 16 + k];
                if (rA < c + hh){ s_dA = tid * 16 + k; s_cloA = c; break; }
                c += hh;
            }
        }
        if (rB >= plo && rB < phi){
            unsigned c = plo;
            for (int k = 0; k < 16; ++k){
                unsigned hh = hist[tid * 16 + k];
                if (rB < c + hh){ s_dB = tid * 16 + k; s_cloB = c; break; }
                c += hh;
            }
        }
        __syncthreads();
        unsigned dA = s_dA, dB = s_dB;
        if (dA != dB){
            unsigned locA = 0u, locB = 0xFFFFFFFFu;
            #pragma unroll
            for (int e = 0; e < 64; ++e){
                unsigned d = key[e] >> 20;
                if (d == dA) locA = max(locA, key[e]);
                if (d == dB) locB = min(locB, key[e]);
            }
            reduce_maxmin(locA, locB, tid, redA, redB, &s_keyA, &s_keyB);
            done = true;
        } else {
            prefVal = dA << 20; prefMask = 0xFFFu << 20;
            rA -= s_cloA; rB -= s_cloB;
            #pragma unroll
            for (int e = 0; e < 64; ++e){
                if ((key[e] >> 20) == dA){
                    unsigned id2 = atomicAdd(&s_cnt, 1u);
                    if (id2 < SEL_CAP) cand[id2] = key[e];
                }
            }
            __syncthreads();
        }
    }

    // ---- levels 1..3: 8,8,4 bits over candidate list (or registers) ----
    if (!done){
        unsigned nc = s_cnt;
        bool useCand = (nc <= SEL_CAP);
        const int shifts[3] = {12, 4, 0};
        const int bitsv[3]  = {8, 8, 4};
        for (int lvl = 0; lvl < 3 && !done; ++lvl){
            int shift = shifts[lvl];
            unsigned nb = 1u << bitsv[lvl];
            unsigned msk = nb - 1u;
            if (tid < (int)nb) hist[tid] = 0u;
            __syncthreads();
            if (useCand){
                for (unsigned i = tid; i < nc; i += 256){
                    unsigned k2 = cand[i];
                    if ((k2 & prefMask) == prefVal)
                        atomicAdd(&hist[(k2 >> shift) & msk], 1u);
                }
            } else {
                #pragma unroll
                for (int e = 0; e < 64; ++e){
                    if ((key[e] & prefMask) == prefVal)
                        atomicAdd(&hist[(key[e] >> shift) & msk], 1u);
                }
            }
            __syncthreads();
            spart[tid] = (tid < (int)nb) ? hist[tid] : 0u;
            __syncthreads();
            for (int off = 1; off < 256; off <<= 1){
                unsigned v = (tid >= off) ? spart[tid - off] : 0u;
                __syncthreads();
                spart[tid] += v;
                __syncthreads();
            }
            unsigned plo = (tid == 0) ? 0u : spart[tid - 1];
            unsigned phi = spart[tid];
            if (tid < (int)nb){
                if (rA >= plo && rA < phi){ s_dA = tid; s_cloA = plo; }
                if (rB >= plo && rB < phi){ s_dB = tid; s_cloB = plo; }
            }
            __syncthreads();
            unsigned dA = s_dA, dB = s_dB;
            if (dA != dB){
                unsigned mA = prefMask | (msk << shift);
                unsigned vAp = prefVal | (dA << shift);
                unsigned vBp = prefVal | (dB << shift);
                unsigned locA = 0u, locB = 0xFFFFFFFFu;
                if (useCand){
                    for (unsigned i = tid; i < nc; i += 256){
                        unsigned k2 = cand[i];
                        if ((k2 & mA) == vAp) locA = max(locA, k2);
                        if ((k2 & mA) == vBp) locB = min(locB, k2);
                    }
                } else {
                    #pragma unroll
                    for (int e = 0; e < 64; ++e){
                        if ((key[e] & mA) == vAp) locA = max(locA, key[e]);
                        if ((key[e] & mA) == vBp) locB = min(locB, key[e]);
                    }
                }
                reduce_maxmin(locA, locB, tid, redA, redB, &s_keyA, &s_keyB);
                done = true;
            } else {
                prefVal |= dA << shift;
                prefMask |= msk << shift;
                rA -= s_cloA; rB -= s_cloB;
                if (lvl == 2){
                    if (tid == 0){ s_keyA = prefVal; s_keyB = prefVal; }
                    done = true;
                }
                __syncthreads();
            }
        }
    }

    if (tid == 0){
        float vlo = key2f(s_keyA);
        float vhi = key2f(s_keyB);
        float idxq = 0.95f * 16383.0f;
        float frac = idxq - floorf(idxq);
        throut[bc] = vlo * (1.0f - frac) + vhi * frac;
    }
}

// K1b: tiled mask + pools, 16 output rows/block, fused passes.
// Writes outp (bf16) and d1 (bf16).
__global__ __launch_bounds__(256) void k1b_prop(
    const float* __restrict__ x, const float* __restrict__ thrbuf,
    unsigned short* __restrict__ outp, unsigned short* __restrict__ d1g, float g1)
{
    __shared__ __align__(16) float C0[21 * 128];
    __shared__ __align__(16) float A [21 * 128];   // reused as H5[19*64] in pass3
    __shared__ __align__(16) float A1[19 * 128];

    const int tid = threadIdx.x;
    const unsigned blk = blockIdx.x;
    const unsigned bc = blk >> 3;
    const int r0 = (int)(blk & 7u) * 16;

    const float thr = thrbuf[bc];
    const float4* xp4 = (const float4*)(x + (size_t)bc * HW_);

    // pass 1: 21 rows: load, mask -> C0; horizontal max3 via shuffles -> A
    #pragma unroll
    for (int p = 0; p < 3; ++p){
        int i = tid + p * 256;
        if (i < 21 * 32){
            int la = i >> 5, c4 = i & 31;
            int r = r0 - 3 + la;
            float4 c;
            if (r >= 0 && r < 128){
                float4 v = xp4[r * 32 + c4];
                c.x = (v.x >= thr) ? v.x : 0.0f;
                c.y = (v.y >= thr) ? v.y : 0.0f;
                c.z = (v.z >= thr) ? v.z : 0.0f;
                c.w = (v.w >= thr) ? v.w : 0.0f;
            } else {
                c.x = c.y = c.z = c.w = -FLT_MAX;
            }
            ((float4*)C0)[i] = c;
            float lf = __shfl_up(c.w, 1);
            float rt = __shfl_down(c.x, 1);
            if (c4 == 0)  lf = -FLT_MAX;
            if (c4 == 31) rt = -FLT_MAX;
            float4 a;
            a.x = fmaxf(fmaxf(lf,  c.x), c.y);
            a.y = fmaxf(fmaxf(c.x, c.y), c.z);
            a.z = fmaxf(fmaxf(c.y, c.z), c.w);
            a.w = fmaxf(fmaxf(c.z, c.w), rt);
            ((float4*)A)[i] = a;
        }
    }
    __syncthreads();

    // pass 2: vertical max3 * 0.99 -> A1 (19 rows); outp (bf16) for 16 output rows
    {
        unsigned short* op = outp + (size_t)bc * HW_;
        #pragma unroll
        for (int p = 0; p < 10; ++p){
            int i = tid + p * 256;
            if (i < 19 * 128){
                int la1 = i >> 7, j = i & 127;
                float m = fmaxf(fmaxf(A[la1 * 128 + j], A[(la1 + 1) * 128 + j]),
                                A[(la1 + 2) * 128 + j]);
                float a1 = 0.99f * m;
                A1[i] = a1;
                if (la1 >= 2 && la1 < 18){
                    float c0 = C0[(la1 + 1) * 128 + j];
                    op[(r0 + la1 - 2) * 128 + j] = f2bf(fmaxf(c0, a1));
                }
            }
        }
    }
    __syncthreads();

    // pass 3: horizontal 5-tap at even centers over A1 -> H5 (alias of A)
    float* H5 = A;
    #pragma unroll
    for (int p = 0; p < 5; ++p){
        int i = tid + p * 256;
        if (i < 19 * 64){
            int lr = i >> 6, ci = i & 63;
            int c = 2 * ci;
            const float* row = A1 + lr * 128;
            float m = fmaxf(row[c], row[c + 1]);
            if (ci > 0)  m = fmaxf(m, fmaxf(row[c - 1], row[c - 2]));
            if (ci < 63) m = fmaxf(m, row[c + 2]);
            H5[i] = m;
        }
    }
    __syncthreads();

    // pass 4: vertical 5-tap stride-2 + scale -> d1 rows r0/2 .. r0/2+7 (bf16)
    {
        unsigned short* dp = d1g + (size_t)bc * 4096;
        #pragma unroll
        for (int p = 0; p < 2; ++p){
            int i = tid + p * 256;
            int li = i >> 6, j = i & 63;
            int lr = 2 * li;
            float m = fmaxf(fmaxf(H5[lr * 64 + j], H5[(lr + 1) * 64 + j]),
                     fmaxf(fmaxf(H5[(lr + 2) * 64 + j], H5[(lr + 3) * 64 + j]),
                           H5[(lr + 4) * 64 + j]));
            dp[(r0 / 2 + li) * 64 + j] = f2bf(g1 * m);
        }
    }
}

// K2: 64x64 chain d2..d5, m64 = max(d1..d5), in-place over d1 buffer (bf16 io)
__global__ __launch_bounds__(256) void k2_chain(
    unsigned short* __restrict__ dm, float g2, float g3, float g4, float g5)
{
    __shared__ __align__(16) float D[4096];
    __shared__ __align__(16) float T[4096];
    __shared__ __align__(16) float M[4096];
    const int tid = threadIdx.x;
    const unsigned bc = blockIdx.x;
    unsigned short* p = dm + (size_t)bc * 4096;
    const uint4* p4 = (const uint4*)p;   // 8 bf16 per load
    #pragma unroll
    for (int k = 0; k < 2; ++k){
        uint4 v = p4[tid + k * 256];
        int b8 = (tid + k * 256) * 8;
        unsigned w[4] = {v.x, v.y, v.z, v.w};
        #pragma unroll
        for (int e = 0; e < 4; ++e){
            float f0 = __uint_as_float(w[e] << 16);
            float f1 = __uint_as_float(w[e] & 0xFFFF0000u);
            D[b8 + 2*e]     = f0; M[b8 + 2*e]     = f0;
            D[b8 + 2*e + 1] = f1; M[b8 + 2*e + 1] = f1;
        }
    }
    __syncthreads();
    const float gs[4] = {g2, g3, g4, g5};
    for (int it = 0; it < 4; ++it){
        float g = gs[it];
        #pragma unroll 4
        for (int k = 0; k < 16; ++k){
            int q = tid + k * 256;
            int j = q & 63;
            float m = D[q];
            if (j > 0)  m = fmaxf(m, D[q - 1]);
            if (j < 63) m = fmaxf(m, D[q + 1]);
            T[q] = m;
        }
        __syncthreads();
        #pragma unroll 4
        for (int k = 0; k < 16; ++k){
            int q = tid + k * 256;
            int r = q >> 6;
            float m = T[q];
            if (r > 0)  m = fmaxf(m, T[q - 64]);
            if (r < 63) m = fmaxf(m, T[q + 64]);
            float v = g * m;
            D[q] = v;
            M[q] = fmaxf(M[q], v);
        }
        __syncthreads();
    }
    uint4* po = (uint4*)p;
    #pragma unroll
    for (int k = 0; k < 2; ++k){
        int b8 = (tid + k * 256) * 8;
        unsigned w[4];
        #pragma unroll
        for (int e = 0; e < 4; ++e){
            unsigned lo = (unsigned)f2bf(M[b8 + 2*e]);
            unsigned hi = (unsigned)f2bf(M[b8 + 2*e + 1]);
            w[e] = lo | (hi << 16);
        }
        uint4 v = {w[0], w[1], w[2], w[3]};
        po[tid + k * 256] = v;
    }
}

// K3: fused  out' = max(outp, up(m64)) -> h = relu(W1 out'+b1) ->
//            R = sigmoid(W2 h + b2) -> y = x*R
// 1 px/thread, 1024 blocks (4 blocks/CU). outp/m64 read as bf16.
__global__ __launch_bounds__(256) void k3_mlp(
    const float* __restrict__ x, const unsigned short* __restrict__ outp,
    const unsigned short* __restrict__ m64,
    const float* __restrict__ w1, const float* __restrict__ b1,
    const float* __restrict__ w2, const float* __restrict__ b2,
    float* __restrict__ y)
{
    __shared__ __align__(16) float W1s[256 * 16];  // [c][m]
    __shared__ __align__(16) float W2s[256 * 16];  // [c][m]
    __shared__ float B1s[16];
    __shared__ float B2s[256];
    const int tid = threadIdx.x;
    const int blk = blockIdx.x;
    const int b = blk >> 6;
    const int t = blk & 63;

    for (int q = tid; q < 4096; q += 256){
        int c = q >> 4, m = q & 15;
        W1s[q] = w1[m * 256 + c];
        W2s[q] = w2[q];
    }
    if (tid < 16) B1s[tid] = b1[tid];
    B2s[tid] = b2[tid];
    __syncthreads();

    const int pix = t * 256 + tid;
    const int mi = (pix >> 8) * 64 + ((pix & 127) >> 1);
    const size_t base = (size_t)b * 256 * HW_;
    const size_t mbase = (size_t)b * 256 * 4096;

    float h[16];
    #pragma unroll
    for (int m = 0; m < 16; ++m) h[m] = 0.0f;

    #pragma unroll 4
    for (int c = 0; c < 256; ++c){
        float o  = bf2f(outp[base + (size_t)c * HW_ + pix]);
        float mo = bf2f(m64[mbase + (size_t)c * 4096 + mi]);
        o = fmaxf(o, mo);
        const float4* wr = (const float4*)&W1s[c * 16];
        float4 a0 = wr[0], a1 = wr[1], a2 = wr[2], a3 = wr[3];
        h[0]  = fmaf(a0.x, o, h[0]);  h[1]  = fmaf(a0.y, o, h[1]);
        h[2]  = fmaf(a0.z, o, h[2]);  h[3]  = fmaf(a0.w, o, h[3]);
        h[4]  = fmaf(a1.x, o, h[4]);  h[5]  = fmaf(a1.y, o, h[5]);
        h[6]  = fmaf(a1.z, o, h[6]);  h[7]  = fmaf(a1.w, o, h[7]);
        h[8]  = fmaf(a2.x, o, h[8]);  h[9]  = fmaf(a2.y, o, h[9]);
        h[10] = fmaf(a2.z, o, h[10]); h[11] = fmaf(a2.w, o, h[11]);
        h[12] = fmaf(a3.x, o, h[12]); h[13] = fmaf(a3.y, o, h[13]);
        h[14] = fmaf(a3.z, o, h[14]); h[15] = fmaf(a3.w, o, h[15]);
    }
    #pragma unroll
    for (int m = 0; m < 16; ++m) h[m] = fmaxf(h[m] + B1s[m], 0.0f);

    #pragma unroll 4
    for (int c = 0; c < 256; ++c){
        const float4* wr = (const float4*)&W2s[c * 16];
        float4 a0 = wr[0], a1 = wr[1], a2 = wr[2], a3 = wr[3];
        float acc = B2s[c];
        acc += a0.x * h[0]  + a0.y * h[1]  + a0.z * h[2]  + a0.w * h[3];
        acc += a1.x * h[4]  + a1.y * h[5]  + a1.z * h[6]  + a1.w * h[7];
        acc += a2.x * h[8]  + a2.y * h[9]  + a2.z * h[10] + a2.w * h[11];
        acc += a3.x * h[12] + a3.y * h[13] + a3.z * h[14] + a3.w * h[15];
        float R = 1.0f / (1.0f + __expf(-acc));
        float xv = x[base + (size_t)c * HW_ + pix];
        y[base + (size_t)c * HW_ + pix] = xv * R;
    }
}

extern "C" void kernel_launch(void* const* d_in, const int* in_sizes, int n_in,
                              void* d_out, int out_size, void* d_ws, size_t ws_size,
                              hipStream_t stream) {
    const float* x  = (const float*)d_in[0];
    const float* w1 = (const float*)d_in[1];
    const float* b1 = (const float*)d_in[2];
    const float* w2 = (const float*)d_in[3];
    const float* b2 = (const float*)d_in[4];
    float* y  = (float*)d_out;
    char* ws = (char*)d_ws;

    unsigned short* outp = (unsigned short*)ws;                      // 134 MB
    unsigned short* d1   = (unsigned short*)(ws + 134217728);        // 33.5 MB (reused as m64)
    float*          thrb = (float*)(ws + 134217728 + 33554432);      // 16 KB

    float g[6];
    for (int i = 0; i < 6; ++i) g[i] = (float)std::pow(0.99, (double)(1 << i));

    k1a_thr <<<4096, 256, 0, stream>>>(x, thrb);
    k1b_prop<<<32768, 256, 0, stream>>>(x, thrb, outp, d1, g[1]);
    k2_chain<<<4096, 256, 0, stream>>>(d1, g[2], g[3], g[4], g[5]);
    k3_mlp  <<<1024, 256, 0, stream>>>(x, outp, d1, w1, b1, w2, b2, y);
}

// Round 5
// 471.720 us; speedup vs baseline: 1.4571x; 1.1639x over previous
//
#include <hip/hip_runtime.h>
#include <cmath>
#include <cfloat>

#define HW_ 16384

__device__ __forceinline__ unsigned f2key(float f){
    unsigned u = __float_as_uint(f);
    return u ^ ((u & 0x80000000u) ? 0xFFFFFFFFu : 0x80000000u);
}
__device__ __forceinline__ float key2f(unsigned k){
    unsigned u = (k & 0x80000000u) ? (k ^ 0x80000000u) : ~k;
    return __uint_as_float(u);
}
// bf16 storage helpers (RNE)
__device__ __forceinline__ unsigned short f2bf(float f){
    unsigned u = __float_as_uint(f);
    unsigned r = u + 0x7FFFu + ((u >> 16) & 1u);
    return (unsigned short)(r >> 16);
}
__device__ __forceinline__ float bf2f(unsigned short s){
    return __uint_as_float((unsigned)s << 16);
}

#define SEL_CAP 1024

__device__ __forceinline__ void reduce_maxmin(unsigned locA, unsigned locB, int tid,
        unsigned* redA, unsigned* redB, unsigned* s_keyA, unsigned* s_keyB)
{
    #pragma unroll
    for (int o = 32; o > 0; o >>= 1){
        locA = max(locA, __shfl_down(locA, o));
        locB = min(locB, __shfl_down(locB, o));
    }
    if ((tid & 63) == 0){ redA[tid >> 6] = locA; redB[tid >> 6] = locB; }
    __syncthreads();
    if (tid == 0){
        unsigned a = redA[0], b = redB[0];
        for (int w = 1; w < 4; ++w){ a = max(a, redA[w]); b = min(b, redB[w]); }
        *s_keyA = a; *s_keyB = b;
    }
    __syncthreads();
}

// K1a: per (b,c) channel quantile threshold via dual-rank radix select.
// Channel keys kept in REGISTERS (64/thread, all indices compile-time).
__global__ __launch_bounds__(256, 4) void k1a_thr(
    const float* __restrict__ x, float* __restrict__ throut)
{
    __shared__ unsigned hist[4096];
    __shared__ unsigned cand[SEL_CAP];
    __shared__ unsigned spart[256];
    __shared__ unsigned redA[4], redB[4];
    __shared__ unsigned s_cnt, s_dA, s_dB, s_cloA, s_cloB, s_keyA, s_keyB;

    const int tid = threadIdx.x;
    const unsigned bc = blockIdx.x;
    const float4* xp4 = (const float4*)(x + (size_t)bc * HW_);

    unsigned key[64];

    #pragma unroll
    for (int k = 0; k < 16; ++k) hist[tid + k * 256] = 0u;
    if (tid == 0) s_cnt = 0u;
    __syncthreads();

    // single global pass: load, convert, 12-bit histogram (bits 31..20)
    // FULLY unrolled so key[] indices are compile-time constants -> VGPRs.
    #pragma unroll
    for (int k = 0; k < 16; ++k){
        float4 v = xp4[tid + k * 256];
        key[4*k+0] = f2key(v.x);
        key[4*k+1] = f2key(v.y);
        key[4*k+2] = f2key(v.z);
        key[4*k+3] = f2key(v.w);
        atomicAdd(&hist[key[4*k+0] >> 20], 1u);
        atomicAdd(&hist[key[4*k+1] >> 20], 1u);
        atomicAdd(&hist[key[4*k+2] >> 20], 1u);
        atomicAdd(&hist[key[4*k+3] >> 20], 1u);
    }
    __syncthreads();

    unsigned rA = 15563u, rB = 15564u;     // ascending ranks (0-based)
    unsigned prefVal = 0u, prefMask = 0u;
    bool done = false;

    // ---- level 0: 12-bit ----
    {
        unsigned part = 0u;
        #pragma unroll
        for (int k = 0; k < 16; ++k) part += hist[tid * 16 + k];
        spart[tid] = part;
        __syncthreads();
        for (int off = 1; off < 256; off <<= 1){
            unsigned v = (tid >= off) ? spart[tid - off] : 0u;
            __syncthreads();
            spart[tid] += v;
            __syncthreads();
        }
        unsigned plo = (tid == 0) ? 0u : spart[tid - 1];
        unsigned phi = spart[tid];
        if (rA >= plo && rA < phi){
            unsigned c = plo;
            for (int k = 0; k < 16; ++k){
                unsigned hh = hist[tid * 16 + k];
                if (rA < c + hh){ s_dA = tid * 16 + k; s_cloA = c; break; }
                c += hh;
            }
        }
        if (rB >= plo && rB < phi){
            unsigned c = plo;
            for (int k = 0; k < 16; ++k){
                unsigned hh = hist[tid * 16 + k];
                if (rB < c + hh){ s_dB = tid * 16 + k; s_cloB = c; break; }
                c += hh;
            }
        }
        __syncthreads();
        unsigned dA = s_dA, dB = s_dB;
        if (dA != dB){
            unsigned locA = 0u, locB = 0xFFFFFFFFu;
            #pragma unroll
            for (int e = 0; e < 64; ++e){
                unsigned d = key[e] >> 20;
                if (d == dA) locA = max(locA, key[e]);
                if (d == dB) locB = min(locB, key[e]);
            }
            reduce_maxmin(locA, locB, tid, redA, redB, &s_keyA, &s_keyB);
            done = true;
        } else {
            prefVal = dA << 20; prefMask = 0xFFFu << 20;
            rA -= s_cloA; rB -= s_cloB;
            #pragma unroll
            for (int e = 0; e < 64; ++e){
                if ((key[e] >> 20) == dA){
                    unsigned id2 = atomicAdd(&s_cnt, 1u);
                    if (id2 < SEL_CAP) cand[id2] = key[e];
                }
            }
            __syncthreads();
        }
    }

    // ---- levels 1..3: 8,8,4 bits over candidate list (or registers) ----
    if (!done){
        unsigned nc = s_cnt;
        bool useCand = (nc <= SEL_CAP);
        const int shifts[3] = {12, 4, 0};
        const int bitsv[3]  = {8, 8, 4};
        for (int lvl = 0; lvl < 3 && !done; ++lvl){
            int shift = shifts[lvl];
            unsigned nb = 1u << bitsv[lvl];
            unsigned msk = nb - 1u;
            if (tid < (int)nb) hist[tid] = 0u;
            __syncthreads();
            if (useCand){
                for (unsigned i = tid; i < nc; i += 256){
                    unsigned k2 = cand[i];
                    if ((k2 & prefMask) == prefVal)
                        atomicAdd(&hist[(k2 >> shift) & msk], 1u);
                }
            } else {
                #pragma unroll
                for (int e = 0; e < 64; ++e){
                    if ((key[e] & prefMask) == prefVal)
                        atomicAdd(&hist[(key[e] >> shift) & msk], 1u);
                }
            }
            __syncthreads();
            spart[tid] = (tid < (int)nb) ? hist[tid] : 0u;
            __syncthreads();
            for (int off = 1; off < 256; off <<= 1){
                unsigned v = (tid >= off) ? spart[tid - off] : 0u;
                __syncthreads();
                spart[tid] += v;
                __syncthreads();
            }
            unsigned plo = (tid == 0) ? 0u : spart[tid - 1];
            unsigned phi = spart[tid];
            if (tid < (int)nb){
                if (rA >= plo && rA < phi){ s_dA = tid; s_cloA = plo; }
                if (rB >= plo && rB < phi){ s_dB = tid; s_cloB = plo; }
            }
            __syncthreads();
            unsigned dA = s_dA, dB = s_dB;
            if (dA != dB){
                unsigned mA = prefMask | (msk << shift);
                unsigned vAp = prefVal | (dA << shift);
                unsigned vBp = prefVal | (dB << shift);
                unsigned locA = 0u, locB = 0xFFFFFFFFu;
                if (useCand){
                    for (unsigned i = tid; i < nc; i += 256){
                        unsigned k2 = cand[i];
                        if ((k2 & mA) == vAp) locA = max(locA, k2);
                        if ((k2 & mA) == vBp) locB = min(locB, k2);
                    }
                } else {
                    #pragma unroll
                    for (int e = 0; e < 64; ++e){
                        if ((key[e] & mA) == vAp) locA = max(locA, key[e]);
                        if ((key[e] & mA) == vBp) locB = min(locB, key[e]);
                    }
                }
                reduce_maxmin(locA, locB, tid, redA, redB, &s_keyA, &s_keyB);
                done = true;
            } else {
                prefVal |= dA << shift;
                prefMask |= msk << shift;
                rA -= s_cloA; rB -= s_cloB;
                if (lvl == 2){
                    if (tid == 0){ s_keyA = prefVal; s_keyB = prefVal; }
                    done = true;
                }
                __syncthreads();
            }
        }
    }

    if (tid == 0){
        float vlo = key2f(s_keyA);
        float vhi = key2f(s_keyB);
        float idxq = 0.95f * 16383.0f;
        float frac = idxq - floorf(idxq);
        throut[bc] = vlo * (1.0f - frac) + vhi * frac;
    }
}

// K1b: tiled mask + pools, 16 output rows/block, fused passes.
// Writes outp (bf16) and d1 (bf16).
__global__ __launch_bounds__(256) void k1b_prop(
    const float* __restrict__ x, const float* __restrict__ thrbuf,
    unsigned short* __restrict__ outp, unsigned short* __restrict__ d1g, float g1)
{
    __shared__ __align__(16) float C0[21 * 128];
    __shared__ __align__(16) float A [21 * 128];   // reused as H5[19*64] in pass3
    __shared__ __align__(16) float A1[19 * 128];

    const int tid = threadIdx.x;
    const unsigned blk = blockIdx.x;
    const unsigned bc = blk >> 3;
    const int r0 = (int)(blk & 7u) * 16;

    const float thr = thrbuf[bc];
    const float4* xp4 = (const float4*)(x + (size_t)bc * HW_);

    // pass 1: 21 rows: load, mask -> C0; horizontal max3 via shuffles -> A
    #pragma unroll
    for (int p = 0; p < 3; ++p){
        int i = tid + p * 256;
        if (i < 21 * 32){
            int la = i >> 5, c4 = i & 31;
            int r = r0 - 3 + la;
            float4 c;
            if (r >= 0 && r < 128){
                float4 v = xp4[r * 32 + c4];
                c.x = (v.x >= thr) ? v.x : 0.0f;
                c.y = (v.y >= thr) ? v.y : 0.0f;
                c.z = (v.z >= thr) ? v.z : 0.0f;
                c.w = (v.w >= thr) ? v.w : 0.0f;
            } else {
                c.x = c.y = c.z = c.w = -FLT_MAX;
            }
            ((float4*)C0)[i] = c;
            float lf = __shfl_up(c.w, 1);
            float rt = __shfl_down(c.x, 1);
            if (c4 == 0)  lf = -FLT_MAX;
            if (c4 == 31) rt = -FLT_MAX;
            float4 a;
            a.x = fmaxf(fmaxf(lf,  c.x), c.y);
            a.y = fmaxf(fmaxf(c.x, c.y), c.z);
            a.z = fmaxf(fmaxf(c.y, c.z), c.w);
            a.w = fmaxf(fmaxf(c.z, c.w), rt);
            ((float4*)A)[i] = a;
        }
    }
    __syncthreads();

    // pass 2: vertical max3 * 0.99 -> A1 (19 rows); outp (bf16) for 16 output rows
    {
        unsigned short* op = outp + (size_t)bc * HW_;
        #pragma unroll
        for (int p = 0; p < 10; ++p){
            int i = tid + p * 256;
            if (i < 19 * 128){
                int la1 = i >> 7, j = i & 127;
                float m = fmaxf(fmaxf(A[la1 * 128 + j], A[(la1 + 1) * 128 + j]),
                                A[(la1 + 2) * 128 + j]);
                float a1 = 0.99f * m;
                A1[i] = a1;
                if (la1 >= 2 && la1 < 18){
                    float c0 = C0[(la1 + 1) * 128 + j];
                    op[(r0 + la1 - 2) * 128 + j] = f2bf(fmaxf(c0, a1));
                }
            }
        }
    }
    __syncthreads();

    // pass 3: horizontal 5-tap at even centers over A1 -> H5 (alias of A)
    float* H5 = A;
    #pragma unroll
    for (int p = 0; p < 5; ++p){
        int i = tid + p * 256;
        if (i < 19 * 64){
            int lr = i >> 6, ci = i & 63;
            int c = 2 * ci;
            const float* row = A1 + lr * 128;
            float m = fmaxf(row[c], row[c + 1]);
            if (ci > 0)  m = fmaxf(m, fmaxf(row[c - 1], row[c - 2]));
            if (ci < 63) m = fmaxf(m, row[c + 2]);
            H5[i] = m;
        }
    }
    __syncthreads();

    // pass 4: vertical 5-tap stride-2 + scale -> d1 rows r0/2 .. r0/2+7 (bf16)
    {
        unsigned short* dp = d1g + (size_t)bc * 4096;
        #pragma unroll
        for (int p = 0; p < 2; ++p){
            int i = tid + p * 256;
            int li = i >> 6, j = i & 63;
            int lr = 2 * li;
            float m = fmaxf(fmaxf(H5[lr * 64 + j], H5[(lr + 1) * 64 + j]),
                     fmaxf(fmaxf(H5[(lr + 2) * 64 + j], H5[(lr + 3) * 64 + j]),
                           H5[(lr + 4) * 64 + j]));
            dp[(r0 / 2 + li) * 64 + j] = f2bf(g1 * m);
        }
    }
}

// K2: 64x64 chain d2..d5, m64 = max(d1..d5), in-place over d1 buffer (bf16 io)
__global__ __launch_bounds__(256) void k2_chain(
    unsigned short* __restrict__ dm, float g2, float g3, float g4, float g5)
{
    __shared__ __align__(16) float D[4096];
    __shared__ __align__(16) float T[4096];
    __shared__ __align__(16) float M[4096];
    const int tid = threadIdx.x;
    const unsigned bc = blockIdx.x;
    unsigned short* p = dm + (size_t)bc * 4096;
    const uint4* p4 = (const uint4*)p;   // 8 bf16 per load
    #pragma unroll
    for (int k = 0; k < 2; ++k){
        uint4 v = p4[tid + k * 256];
        int b8 = (tid + k * 256) * 8;
        unsigned w[4] = {v.x, v.y, v.z, v.w};
        #pragma unroll
        for (int e = 0; e < 4; ++e){
            float f0 = __uint_as_float(w[e] << 16);
            float f1 = __uint_as_float(w[e] & 0xFFFF0000u);
            D[b8 + 2*e]     = f0; M[b8 + 2*e]     = f0;
            D[b8 + 2*e + 1] = f1; M[b8 + 2*e + 1] = f1;
        }
    }
    __syncthreads();
    const float gs[4] = {g2, g3, g4, g5};
    for (int it = 0; it < 4; ++it){
        float g = gs[it];
        #pragma unroll 4
        for (int k = 0; k < 16; ++k){
            int q = tid + k * 256;
            int j = q & 63;
            float m = D[q];
            if (j > 0)  m = fmaxf(m, D[q - 1]);
            if (j < 63) m = fmaxf(m, D[q + 1]);
            T[q] = m;
        }
        __syncthreads();
        #pragma unroll 4
        for (int k = 0; k < 16; ++k){
            int q = tid + k * 256;
            int r = q >> 6;
            float m = T[q];
            if (r > 0)  m = fmaxf(m, T[q - 64]);
            if (r < 63) m = fmaxf(m, T[q + 64]);
            float v = g * m;
            D[q] = v;
            M[q] = fmaxf(M[q], v);
        }
        __syncthreads();
    }
    uint4* po = (uint4*)p;
    #pragma unroll
    for (int k = 0; k < 2; ++k){
        int b8 = (tid + k * 256) * 8;
        unsigned w[4];
        #pragma unroll
        for (int e = 0; e < 4; ++e){
            unsigned lo = (unsigned)f2bf(M[b8 + 2*e]);
            unsigned hi = (unsigned)f2bf(M[b8 + 2*e + 1]);
            w[e] = lo | (hi << 16);
        }
        uint4 v = {w[0], w[1], w[2], w[3]};
        po[tid + k * 256] = v;
    }
}

// K3: fused  out' = max(outp, up(m64)) -> h = relu(W1 out'+b1) ->
//            R = sigmoid(W2 h + b2) -> y = x*R
// 1 px/thread, 1024 blocks (4 blocks/CU). outp/m64 read as bf16.
__global__ __launch_bounds__(256) void k3_mlp(
    const float* __restrict__ x, const unsigned short* __restrict__ outp,
    const unsigned short* __restrict__ m64,
    const float* __restrict__ w1, const float* __restrict__ b1,
    const float* __restrict__ w2, const float* __restrict__ b2,
    float* __restrict__ y)
{
    __shared__ __align__(16) float W1s[256 * 16];  // [c][m]
    __shared__ __align__(16) float W2s[256 * 16];  // [c][m]
    __shared__ float B1s[16];
    __shared__ float B2s[256];
    const int tid = threadIdx.x;
    const int blk = blockIdx.x;
    const int b = blk >> 6;
    const int t = blk & 63;

    for (int q = tid; q < 4096; q += 256){
        int c = q >> 4, m = q & 15;
        W1s[q] = w1[m * 256 + c];
        W2s[q] = w2[q];
    }
    if (tid < 16) B1s[tid] = b1[tid];
    B2s[tid] = b2[tid];
    __syncthreads();

    const int pix = t * 256 + tid;
    const int mi = (pix >> 8) * 64 + ((pix & 127) >> 1);
    const size_t base = (size_t)b * 256 * HW_;
    const size_t mbase = (size_t)b * 256 * 4096;

    float h[16];
    #pragma unroll
    for (int m = 0; m < 16; ++m) h[m] = 0.0f;

    #pragma unroll 4
    for (int c = 0; c < 256; ++c){
        float o  = bf2f(outp[base + (size_t)c * HW_ + pix]);
        float mo = bf2f(m64[mbase + (size_t)c * 4096 + mi]);
        o = fmaxf(o, mo);
        const float4* wr = (const float4*)&W1s[c * 16];
        float4 a0 = wr[0], a1 = wr[1], a2 = wr[2], a3 = wr[3];
        h[0]  = fmaf(a0.x, o, h[0]);  h[1]  = fmaf(a0.y, o, h[1]);
        h[2]  = fmaf(a0.z, o, h[2]);  h[3]  = fmaf(a0.w, o, h[3]);
        h[4]  = fmaf(a1.x, o, h[4]);  h[5]  = fmaf(a1.y, o, h[5]);
        h[6]  = fmaf(a1.z, o, h[6]);  h[7]  = fmaf(a1.w, o, h[7]);
        h[8]  = fmaf(a2.x, o, h[8]);  h[9]  = fmaf(a2.y, o, h[9]);
        h[10] = fmaf(a2.z, o, h[10]); h[11] = fmaf(a2.w, o, h[11]);
        h[12] = fmaf(a3.x, o, h[12]); h[13] = fmaf(a3.y, o, h[13]);
        h[14] = fmaf(a3.z, o, h[14]); h[15] = fmaf(a3.w, o, h[15]);
    }
    #pragma unroll
    for (int m = 0; m < 16; ++m) h[m] = fmaxf(h[m] + B1s[m], 0.0f);

    #pragma unroll 4
    for (int c = 0; c < 256; ++c){
        const float4* wr = (const float4*)&W2s[c * 16];
        float4 a0 = wr[0], a1 = wr[1], a2 = wr[2], a3 = wr[3];
        float acc = B2s[c];
        acc += a0.x * h[0]  + a0.y * h[1]  + a0.z * h[2]  + a0.w * h[3];
        acc += a1.x * h[4]  + a1.y * h[5]  + a1.z * h[6]  + a1.w * h[7];
        acc += a2.x * h[8]  + a2.y * h[9]  + a2.z * h[10] + a2.w * h[11];
        acc += a3.x * h[12] + a3.y * h[13] + a3.z * h[14] + a3.w * h[15];
        float R = 1.0f / (1.0f + __expf(-acc));
        float xv = x[base + (size_t)c * HW_ + pix];
        y[base + (size_t)c * HW_ + pix] = xv * R;
    }
}

extern "C" void kernel_launch(void* const* d_in, const int* in_sizes, int n_in,
                              void* d_out, int out_size, void* d_ws, size_t ws_size,
                              hipStream_t stream) {
    const float* x  = (const float*)d_in[0];
    const float* w1 = (const float*)d_in[1];
    const float* b1 = (const float*)d_in[2];
    const float* w2 = (const float*)d_in[3];
    const float* b2 = (const float*)d_in[4];
    float* y  = (float*)d_out;
    char* ws = (char*)d_ws;

    unsigned short* outp = (unsigned short*)ws;                      // 134 MB
    unsigned short* d1   = (unsigned short*)(ws + 134217728);        // 33.5 MB (reused as m64)
    float*          thrb = (float*)(ws + 134217728 + 33554432);      // 16 KB

    float g[6];
    for (int i = 0; i < 6; ++i) g[i] = (float)std::pow(0.99, (double)(1 << i));

    k1a_thr <<<4096, 256, 0, stream>>>(x, thrb);
    k1b_prop<<<32768, 256, 0, stream>>>(x, thrb, outp, d1, g[1]);
    k2_chain<<<4096, 256, 0, stream>>>(d1, g[2], g[3], g[4], g[5]);
    k3_mlp  <<<1024, 256, 0, stream>>>(x, outp, d1, w1, b1, w2, b2, y);
}

// Round 6
// 401.810 us; speedup vs baseline: 1.7106x; 1.1740x over previous
//
#include <hip/hip_runtime.h>
#include <cmath>
#include <cfloat>

#define HW_ 16384

__device__ __forceinline__ unsigned f2key(float f){
    unsigned u = __float_as_uint(f);
    return u ^ ((u & 0x80000000u) ? 0xFFFFFFFFu : 0x80000000u);
}
__device__ __forceinline__ float key2f(unsigned k){
    unsigned u = (k & 0x80000000u) ? (k ^ 0x80000000u) : ~k;
    return __uint_as_float(u);
}
// bf16 storage helpers (RNE)
__device__ __forceinline__ unsigned short f2bf(float f){
    unsigned u = __float_as_uint(f);
    unsigned r = u + 0x7FFFu + ((u >> 16) & 1u);
    return (unsigned short)(r >> 16);
}
__device__ __forceinline__ float bf2f(unsigned short s){
    return __uint_as_float((unsigned)s << 16);
}
__device__ __forceinline__ float4 unpack2(uint2 p){
    float4 r;
    r.x = __uint_as_float(p.x << 16);
    r.y = __uint_as_float(p.x & 0xFFFF0000u);
    r.z = __uint_as_float(p.y << 16);
    r.w = __uint_as_float(p.y & 0xFFFF0000u);
    return r;
}
__device__ __forceinline__ uint2 pack2(float4 v){
    uint2 p;
    p.x = (unsigned)f2bf(v.x) | ((unsigned)f2bf(v.y) << 16);
    p.y = (unsigned)f2bf(v.z) | ((unsigned)f2bf(v.w) << 16);
    return p;
}
__device__ __forceinline__ float4 max4(float4 a, float4 b){
    float4 r;
    r.x = fmaxf(a.x, b.x); r.y = fmaxf(a.y, b.y);
    r.z = fmaxf(a.z, b.z); r.w = fmaxf(a.w, b.w);
    return r;
}

// K1f: one block per (b,c) channel, 512 threads.
// quantile select (keys in registers) -> mask -> pool3 -> outp(bf16)
// -> 5x5s2 pool -> d1(64x64, LDS) -> 4x pool3_64 chain -> m64(bf16).
__global__ __launch_bounds__(512, 4) void k1f(
    const float* __restrict__ x,
    unsigned short* __restrict__ outp, unsigned short* __restrict__ m64g,
    float g1, float g2, float g3, float g4, float g5)
{
    __shared__ __align__(16) unsigned short C0[16384];  // 32KB: c0/a1 bf16; later D,M f32
    __shared__ __align__(16) unsigned short Ab[16384];  // 32KB: A bf16; later H5 bf16 + T f32
    __shared__ unsigned hist[2048];
    __shared__ unsigned spart[512];
    __shared__ unsigned redA[8], redB[8];
    __shared__ unsigned s_dA, s_dB, s_cloA, s_cloB, s_keyA, s_keyB;

    const int tid = threadIdx.x;
    const unsigned bc = blockIdx.x;
    const float4* xp4 = (const float4*)(x + (size_t)bc * HW_);

    unsigned key[32];

    // ---- P0: init hist, load x, build keys, 11-bit histogram ----
    #pragma unroll
    for (int k = 0; k < 4; ++k) hist[tid + k * 512] = 0u;
    __syncthreads();
    #pragma unroll
    for (int k = 0; k < 8; ++k){
        float4 v = xp4[tid + k * 512];
        key[4*k+0] = f2key(v.x);
        key[4*k+1] = f2key(v.y);
        key[4*k+2] = f2key(v.z);
        key[4*k+3] = f2key(v.w);
        atomicAdd(&hist[key[4*k+0] >> 21], 1u);
        atomicAdd(&hist[key[4*k+1] >> 21], 1u);
        atomicAdd(&hist[key[4*k+2] >> 21], 1u);
        atomicAdd(&hist[key[4*k+3] >> 21], 1u);
    }
    __syncthreads();

    // ---- P1: dual-rank select ----
    unsigned rA = 15563u, rB = 15564u;
    unsigned prefVal = 0u, prefMask = 0u;
    bool done = false;

    {   // level 0: 11 bits (2048 bins, 4/thread)
        unsigned part = hist[tid*4] + hist[tid*4+1] + hist[tid*4+2] + hist[tid*4+3];
        spart[tid] = part;
        __syncthreads();
        for (int off = 1; off < 512; off <<= 1){
            unsigned v = (tid >= off) ? spart[tid - off] : 0u;
            __syncthreads();
            spart[tid] += v;
            __syncthreads();
        }
        unsigned plo = (tid == 0) ? 0u : spart[tid - 1];
        unsigned phi = spart[tid];
        if (rA >= plo && rA < phi){
            unsigned c = plo;
            #pragma unroll
            for (int k = 0; k < 4; ++k){
                unsigned hh = hist[tid*4+k];
                if (rA < c + hh){ s_dA = tid*4+k; s_cloA = c; break; }
                c += hh;
            }
        }
        if (rB >= plo && rB < phi){
            unsigned c = plo;
            #pragma unroll
            for (int k = 0; k < 4; ++k){
                unsigned hh = hist[tid*4+k];
                if (rB < c + hh){ s_dB = tid*4+k; s_cloB = c; break; }
                c += hh;
            }
        }
        __syncthreads();
        unsigned dA = s_dA, dB = s_dB;
        if (dA != dB){
            unsigned locA = 0u, locB = 0xFFFFFFFFu;
            #pragma unroll
            for (int e = 0; e < 32; ++e){
                unsigned d = key[e] >> 21;
                if (d == dA) locA = max(locA, key[e]);
                if (d == dB) locB = min(locB, key[e]);
            }
            #pragma unroll
            for (int o = 32; o > 0; o >>= 1){
                locA = max(locA, __shfl_down(locA, o));
                locB = min(locB, __shfl_down(locB, o));
            }
            if ((tid & 63) == 0){ redA[tid >> 6] = locA; redB[tid >> 6] = locB; }
            __syncthreads();
            if (tid == 0){
                unsigned a = redA[0], b = redB[0];
                for (int w = 1; w < 8; ++w){ a = max(a, redA[w]); b = min(b, redB[w]); }
                s_keyA = a; s_keyB = b;
            }
            __syncthreads();
            done = true;
        } else {
            prefVal = dA << 21; prefMask = 0x7FFu << 21;
            rA -= s_cloA; rB -= s_cloB;
            __syncthreads();
        }
    }

    if (!done){
        const int shifts[3] = {13, 5, 0};
        const int bitsv[3]  = {8, 8, 5};
        for (int lvl = 0; lvl < 3 && !done; ++lvl){
            int shift = shifts[lvl];
            unsigned nb = 1u << bitsv[lvl];
            unsigned msk = nb - 1u;
            if (tid < (int)nb) hist[tid] = 0u;
            __syncthreads();
            #pragma unroll
            for (int e = 0; e < 32; ++e){
                if ((key[e] & prefMask) == prefVal)
                    atomicAdd(&hist[(key[e] >> shift) & msk], 1u);
            }
            __syncthreads();
            spart[tid] = (tid < (int)nb) ? hist[tid] : 0u;
            __syncthreads();
            for (int off = 1; off < 512; off <<= 1){
                unsigned v = (tid >= off) ? spart[tid - off] : 0u;
                __syncthreads();
                spart[tid] += v;
                __syncthreads();
            }
            unsigned plo = (tid == 0) ? 0u : spart[tid - 1];
            unsigned phi = spart[tid];
            if (tid < (int)nb){
                if (rA >= plo && rA < phi){ s_dA = tid; s_cloA = plo; }
                if (rB >= plo && rB < phi){ s_dB = tid; s_cloB = plo; }
            }
            __syncthreads();
            unsigned dA = s_dA, dB = s_dB;
            if (dA != dB){
                unsigned mA = prefMask | (msk << shift);
                unsigned vAp = prefVal | (dA << shift);
                unsigned vBp = prefVal | (dB << shift);
                unsigned locA = 0u, locB = 0xFFFFFFFFu;
                #pragma unroll
                for (int e = 0; e < 32; ++e){
                    if ((key[e] & mA) == vAp) locA = max(locA, key[e]);
                    if ((key[e] & mA) == vBp) locB = min(locB, key[e]);
                }
                #pragma unroll
                for (int o = 32; o > 0; o >>= 1){
                    locA = max(locA, __shfl_down(locA, o));
                    locB = min(locB, __shfl_down(locB, o));
                }
                if ((tid & 63) == 0){ redA[tid >> 6] = locA; redB[tid >> 6] = locB; }
                __syncthreads();
                if (tid == 0){
                    unsigned a = redA[0], b = redB[0];
                    for (int w = 1; w < 8; ++w){ a = max(a, redA[w]); b = min(b, redB[w]); }
                    s_keyA = a; s_keyB = b;
                }
                __syncthreads();
                done = true;
            } else {
                prefVal |= dA << shift;
                prefMask |= msk << shift;
                rA -= s_cloA; rB -= s_cloB;
                if (lvl == 2){
                    if (tid == 0){ s_keyA = prefVal; s_keyB = prefVal; }
                    done = true;
                }
                __syncthreads();
            }
        }
    }

    float vlo = key2f(s_keyA);
    float vhi = key2f(s_keyB);
    float idxq = 0.95f * 16383.0f;
    float frac = idxq - floorf(idxq);
    const float thr = vlo * (1.0f - frac) + vhi * frac;

    // ---- P2: mask (from registers) -> C0 bf16; hmax3 via shuffles -> Ab bf16 ----
    #pragma unroll
    for (int k = 0; k < 8; ++k){
        int i = tid + k * 512;          // float4 index 0..4095
        int c4 = i & 31;
        float4 c;
        {
            float f0 = key2f(key[4*k+0]); c.x = (f0 >= thr) ? f0 : 0.0f;
            float f1 = key2f(key[4*k+1]); c.y = (f1 >= thr) ? f1 : 0.0f;
            float f2 = key2f(key[4*k+2]); c.z = (f2 >= thr) ? f2 : 0.0f;
            float f3 = key2f(key[4*k+3]); c.w = (f3 >= thr) ? f3 : 0.0f;
        }
        ((uint2*)C0)[i] = pack2(c);
        float lf = __shfl_up(c.w, 1);
        float rt = __shfl_down(c.x, 1);
        if (c4 == 0)  lf = -FLT_MAX;
        if (c4 == 31) rt = -FLT_MAX;
        float4 a;
        a.x = fmaxf(fmaxf(lf,  c.x), c.y);
        a.y = fmaxf(fmaxf(c.x, c.y), c.z);
        a.z = fmaxf(fmaxf(c.y, c.z), c.w);
        a.w = fmaxf(fmaxf(c.z, c.w), rt);
        ((uint2*)Ab)[i] = pack2(a);
    }
    __syncthreads();

    // ---- P3: vmax3*0.99 -> a1; outp = max(c0,a1) -> global; a1 -> C0 (in place) ----
    {
        uint2* op2 = (uint2*)(outp + (size_t)bc * HW_);
        #pragma unroll
        for (int k = 0; k < 8; ++k){
            int i = tid + k * 512;
            int r = i >> 5;
            float4 m = unpack2(((uint2*)Ab)[i]);
            if (r > 0)   m = max4(m, unpack2(((uint2*)Ab)[i - 32]));
            if (r < 127) m = max4(m, unpack2(((uint2*)Ab)[i + 32]));
            float4 a1;
            a1.x = 0.99f * m.x; a1.y = 0.99f * m.y;
            a1.z = 0.99f * m.z; a1.w = 0.99f * m.w;
            float4 c0 = unpack2(((uint2*)C0)[i]);
            op2[i] = pack2(max4(c0, a1));
            ((uint2*)C0)[i] = pack2(a1);
        }
    }
    __syncthreads();

    // ---- P4: horizontal 5-tap stride-2 over a1(C0) -> H5 bf16 (Ab[0:8192]) ----
    unsigned short* H5 = Ab;
    #pragma unroll
    for (int k = 0; k < 16; ++k){
        int j = tid + k * 512;          // 0..8191
        int r = j >> 6, ci = j & 63;
        const unsigned short* row = C0 + r * 128;
        int c = 2 * ci;
        float m = fmaxf(bf2f(row[c]), bf2f(row[c + 1]));
        if (ci > 0)  m = fmaxf(m, fmaxf(bf2f(row[c - 1]), bf2f(row[c - 2])));
        if (ci < 63) m = fmaxf(m, bf2f(row[c + 2]));
        H5[j] = f2bf(m);
    }
    __syncthreads();

    // ---- P5: vertical 5-tap stride-2 *g1 -> D f32; M = D (C0 region) ----
    float* Df = (float*)C0;
    float* Mf = Df + 4096;
    #pragma unroll
    for (int k = 0; k < 8; ++k){
        int q = tid + k * 512;          // 0..4095
        int ii = q >> 6, j = q & 63;
        int rr = 2 * ii;
        float m = fmaxf(bf2f(H5[rr * 64 + j]), bf2f(H5[(rr + 1) * 64 + j]));
        if (rr >= 1) m = fmaxf(m, bf2f(H5[(rr - 1) * 64 + j]));
        if (rr >= 2) m = fmaxf(m, bf2f(H5[(rr - 2) * 64 + j]));
        if (rr + 2 <= 127) m = fmaxf(m, bf2f(H5[(rr + 2) * 64 + j]));
        float d = g1 * m;
        Df[q] = d; Mf[q] = d;
    }
    __syncthreads();

    // ---- P6: chain x4 on 64x64 (T f32 in Ab[16KB:32KB]) ----
    float* Tf = (float*)(Ab + 8192);
    const float gs[4] = {g2, g3, g4, g5};
    for (int it = 0; it < 4; ++it){
        float g = gs[it];
        #pragma unroll
        for (int k = 0; k < 8; ++k){
            int q = tid + k * 512;
            int j = q & 63;
            float m = Df[q];
            if (j > 0)  m = fmaxf(m, Df[q - 1]);
            if (j < 63) m = fmaxf(m, Df[q + 1]);
            Tf[q] = m;
        }
        __syncthreads();
        #pragma unroll
        for (int k = 0; k < 8; ++k){
            int q = tid + k * 512;
            int r = q >> 6;
            float m = Tf[q];
            if (r > 0)  m = fmaxf(m, Tf[q - 64]);
            if (r < 63) m = fmaxf(m, Tf[q + 64]);
            float v = g * m;
            Df[q] = v;
            Mf[q] = fmaxf(Mf[q], v);
        }
        __syncthreads();
    }

    // ---- P7: write m64 bf16 ----
    {
        unsigned short* mp = m64g + (size_t)bc * 4096;
        #pragma unroll
        for (int k = 0; k < 8; ++k){
            int q = tid + k * 512;
            mp[q] = f2bf(Mf[q]);
        }
    }
}

// K3: fused  out' = max(outp, up(m64)) -> h = relu(W1 out'+b1) ->
//            R = sigmoid(W2 h + b2) -> y = x*R
// 1 px/thread, 1024 blocks (4 blocks/CU). outp/m64 read as bf16.
__global__ __launch_bounds__(256) void k3_mlp(
    const float* __restrict__ x, const unsigned short* __restrict__ outp,
    const unsigned short* __restrict__ m64,
    const float* __restrict__ w1, const float* __restrict__ b1,
    const float* __restrict__ w2, const float* __restrict__ b2,
    float* __restrict__ y)
{
    __shared__ __align__(16) float W1s[256 * 16];  // [c][m]
    __shared__ __align__(16) float W2s[256 * 16];  // [c][m]
    __shared__ float B1s[16];
    __shared__ float B2s[256];
    const int tid = threadIdx.x;
    const int blk = blockIdx.x;
    const int b = blk >> 6;
    const int t = blk & 63;

    for (int q = tid; q < 4096; q += 256){
        int c = q >> 4, m = q & 15;
        W1s[q] = w1[m * 256 + c];
        W2s[q] = w2[q];
    }
    if (tid < 16) B1s[tid] = b1[tid];
    B2s[tid] = b2[tid];
    __syncthreads();

    const int pix = t * 256 + tid;
    const int mi = (pix >> 8) * 64 + ((pix & 127) >> 1);
    const size_t base = (size_t)b * 256 * HW_;
    const size_t mbase = (size_t)b * 256 * 4096;

    float h[16];
    #pragma unroll
    for (int m = 0; m < 16; ++m) h[m] = 0.0f;

    #pragma unroll 4
    for (int c = 0; c < 256; ++c){
        float o  = bf2f(outp[base + (size_t)c * HW_ + pix]);
        float mo = bf2f(m64[mbase + (size_t)c * 4096 + mi]);
        o = fmaxf(o, mo);
        const float4* wr = (const float4*)&W1s[c * 16];
        float4 a0 = wr[0], a1 = wr[1], a2 = wr[2], a3 = wr[3];
        h[0]  = fmaf(a0.x, o, h[0]);  h[1]  = fmaf(a0.y, o, h[1]);
        h[2]  = fmaf(a0.z, o, h[2]);  h[3]  = fmaf(a0.w, o, h[3]);
        h[4]  = fmaf(a1.x, o, h[4]);  h[5]  = fmaf(a1.y, o, h[5]);
        h[6]  = fmaf(a1.z, o, h[6]);  h[7]  = fmaf(a1.w, o, h[7]);
        h[8]  = fmaf(a2.x, o, h[8]);  h[9]  = fmaf(a2.y, o, h[9]);
        h[10] = fmaf(a2.z, o, h[10]); h[11] = fmaf(a2.w, o, h[11]);
        h[12] = fmaf(a3.x, o, h[12]); h[13] = fmaf(a3.y, o, h[13]);
        h[14] = fmaf(a3.z, o, h[14]); h[15] = fmaf(a3.w, o, h[15]);
    }
    #pragma unroll
    for (int m = 0; m < 16; ++m) h[m] = fmaxf(h[m] + B1s[m], 0.0f);

    #pragma unroll 4
    for (int c = 0; c < 256; ++c){
        const float4* wr = (const float4*)&W2s[c * 16];
        float4 a0 = wr[0], a1 = wr[1], a2 = wr[2], a3 = wr[3];
        float acc = B2s[c];
        acc += a0.x * h[0]  + a0.y * h[1]  + a0.z * h[2]  + a0.w * h[3];
        acc += a1.x * h[4]  + a1.y * h[5]  + a1.z * h[6]  + a1.w * h[7];
        acc += a2.x * h[8]  + a2.y * h[9]  + a2.z * h[10] + a2.w * h[11];
        acc += a3.x * h[12] + a3.y * h[13] + a3.z * h[14] + a3.w * h[15];
        float R = 1.0f / (1.0f + __expf(-acc));
        float xv = x[base + (size_t)c * HW_ + pix];
        y[base + (size_t)c * HW_ + pix] = xv * R;
    }
}

extern "C" void kernel_launch(void* const* d_in, const int* in_sizes, int n_in,
                              void* d_out, int out_size, void* d_ws, size_t ws_size,
                              hipStream_t stream) {
    const float* x  = (const float*)d_in[0];
    const float* w1 = (const float*)d_in[1];
    const float* b1 = (const float*)d_in[2];
    const float* w2 = (const float*)d_in[3];
    const float* b2 = (const float*)d_in[4];
    float* y  = (float*)d_out;
    char* ws = (char*)d_ws;

    unsigned short* outp = (unsigned short*)ws;                 // 134 MB
    unsigned short* m64  = (unsigned short*)(ws + 134217728);   // 33.5 MB

    float g[6];
    for (int i = 0; i < 6; ++i) g[i] = (float)std::pow(0.99, (double)(1 << i));

    k1f<<<4096, 512, 0, stream>>>(x, outp, m64, g[1], g[2], g[3], g[4], g[5]);
    k3_mlp<<<1024, 256, 0, stream>>>(x, outp, m64, w1, b1, w2, b2, y);
}

// Round 7
// 386.595 us; speedup vs baseline: 1.7780x; 1.0394x over previous
//
#include <hip/hip_runtime.h>
#include <cmath>
#include <cfloat>

#define HW_ 16384

__device__ __forceinline__ unsigned f2key(float f){
    unsigned u = __float_as_uint(f);
    return u ^ ((u & 0x80000000u) ? 0xFFFFFFFFu : 0x80000000u);
}
__device__ __forceinline__ float key2f(unsigned k){
    unsigned u = (k & 0x80000000u) ? (k ^ 0x80000000u) : ~k;
    return __uint_as_float(u);
}
// bf16 storage helpers (RNE)
__device__ __forceinline__ unsigned short f2bf(float f){
    unsigned u = __float_as_uint(f);
    unsigned r = u + 0x7FFFu + ((u >> 16) & 1u);
    return (unsigned short)(r >> 16);
}
__device__ __forceinline__ float bf2f(unsigned short s){
    return __uint_as_float((unsigned)s << 16);
}
__device__ __forceinline__ float4 unpack2(uint2 p){
    float4 r;
    r.x = __uint_as_float(p.x << 16);
    r.y = __uint_as_float(p.x & 0xFFFF0000u);
    r.z = __uint_as_float(p.y << 16);
    r.w = __uint_as_float(p.y & 0xFFFF0000u);
    return r;
}
__device__ __forceinline__ uint2 pack2(float4 v){
    uint2 p;
    p.x = (unsigned)f2bf(v.x) | ((unsigned)f2bf(v.y) << 16);
    p.y = (unsigned)f2bf(v.z) | ((unsigned)f2bf(v.w) << 16);
    return p;
}
__device__ __forceinline__ float4 max4(float4 a, float4 b){
    float4 r;
    r.x = fmaxf(a.x, b.x); r.y = fmaxf(a.y, b.y);
    r.z = fmaxf(a.z, b.z); r.w = fmaxf(a.w, b.w);
    return r;
}
// 64-lane inclusive scan, no barriers
__device__ __forceinline__ unsigned wscan_incl(unsigned v, int lane){
    #pragma unroll
    for (int o = 1; o < 64; o <<= 1){
        unsigned u = __shfl_up(v, o);
        v += (lane >= o) ? u : 0u;
    }
    return v;
}

// K1f: one block per (b,c) channel, 512 threads.
// quantile select (keys in registers, wave-segmented scans) -> mask -> pool3
// -> outp(bf16) -> 5x5s2 pool -> d1(64x64, LDS) -> 4x pool3_64 chain -> m64(bf16).
__global__ __launch_bounds__(512, 4) void k1f(
    const float* __restrict__ x,
    unsigned short* __restrict__ outp, unsigned short* __restrict__ m64g,
    float g1, float g2, float g3, float g4, float g5)
{
    __shared__ __align__(16) unsigned short C0[16384];  // 32KB: c0/a1 bf16; later D,M f32
    __shared__ __align__(16) unsigned short Ab[16384];  // 32KB: A bf16; later H5 bf16 + T f32
    __shared__ unsigned hist[2048];
    __shared__ unsigned wsum[8];
    __shared__ unsigned redA[8], redB[8];
    __shared__ unsigned s_dA, s_dB, s_cloA, s_cloB, s_keyA, s_keyB;

    const int tid = threadIdx.x;
    const int lane = tid & 63;
    const int wid = tid >> 6;
    const unsigned bc = blockIdx.x;
    const float4* xp4 = (const float4*)(x + (size_t)bc * HW_);

    unsigned key[32];

    // ---- P0: init hist, load x, build keys, 11-bit histogram ----
    #pragma unroll
    for (int k = 0; k < 4; ++k) hist[tid + k * 512] = 0u;
    __syncthreads();
    #pragma unroll
    for (int k = 0; k < 8; ++k){
        float4 v = xp4[tid + k * 512];
        key[4*k+0] = f2key(v.x);
        key[4*k+1] = f2key(v.y);
        key[4*k+2] = f2key(v.z);
        key[4*k+3] = f2key(v.w);
        atomicAdd(&hist[key[4*k+0] >> 21], 1u);
        atomicAdd(&hist[key[4*k+1] >> 21], 1u);
        atomicAdd(&hist[key[4*k+2] >> 21], 1u);
        atomicAdd(&hist[key[4*k+3] >> 21], 1u);
    }
    __syncthreads();

    // ---- P1: dual-rank select ----
    unsigned rA = 15563u, rB = 15564u;
    unsigned prefVal = 0u, prefMask = 0u;
    bool done = false;

    {   // level 0: 11 bits (2048 bins, 4/thread), wave-segmented scan
        unsigned part = hist[tid*4] + hist[tid*4+1] + hist[tid*4+2] + hist[tid*4+3];
        unsigned incl = wscan_incl(part, lane);
        if (lane == 63) wsum[wid] = incl;
        __syncthreads();
        unsigned off = 0;
        #pragma unroll
        for (int w = 0; w < 8; ++w) off += (w < wid) ? wsum[w] : 0u;
        unsigned phi = incl + off;
        unsigned plo = phi - part;
        if (rA >= plo && rA < phi){
            unsigned c = plo;
            #pragma unroll
            for (int k = 0; k < 4; ++k){
                unsigned hh = hist[tid*4+k];
                if (rA < c + hh){ s_dA = tid*4+k; s_cloA = c; break; }
                c += hh;
            }
        }
        if (rB >= plo && rB < phi){
            unsigned c = plo;
            #pragma unroll
            for (int k = 0; k < 4; ++k){
                unsigned hh = hist[tid*4+k];
                if (rB < c + hh){ s_dB = tid*4+k; s_cloB = c; break; }
                c += hh;
            }
        }
        __syncthreads();
        unsigned dA = s_dA, dB = s_dB;
        if (dA != dB){
            unsigned locA = 0u, locB = 0xFFFFFFFFu;
            #pragma unroll
            for (int e = 0; e < 32; ++e){
                unsigned d = key[e] >> 21;
                if (d == dA) locA = max(locA, key[e]);
                if (d == dB) locB = min(locB, key[e]);
            }
            #pragma unroll
            for (int o = 32; o > 0; o >>= 1){
                locA = max(locA, __shfl_down(locA, o));
                locB = min(locB, __shfl_down(locB, o));
            }
            if (lane == 0){ redA[wid] = locA; redB[wid] = locB; }
            __syncthreads();
            if (tid == 0){
                unsigned a = redA[0], b = redB[0];
                for (int w = 1; w < 8; ++w){ a = max(a, redA[w]); b = min(b, redB[w]); }
                s_keyA = a; s_keyB = b;
            }
            __syncthreads();
            done = true;
        } else {
            prefVal = dA << 21; prefMask = 0x7FFu << 21;
            rA -= s_cloA; rB -= s_cloB;
            __syncthreads();
        }
    }

    if (!done){
        const int shifts[3] = {13, 5, 0};
        const int bitsv[3]  = {8, 8, 5};
        for (int lvl = 0; lvl < 3 && !done; ++lvl){
            int shift = shifts[lvl];
            unsigned nb = 1u << bitsv[lvl];
            unsigned msk = nb - 1u;
            if (tid < (int)nb) hist[tid] = 0u;
            __syncthreads();
            #pragma unroll
            for (int e = 0; e < 32; ++e){
                if ((key[e] & prefMask) == prefVal)
                    atomicAdd(&hist[(key[e] >> shift) & msk], 1u);
            }
            __syncthreads();
            unsigned part = (tid < (int)nb) ? hist[tid] : 0u;
            unsigned incl = wscan_incl(part, lane);
            if (lane == 63) wsum[wid] = incl;
            __syncthreads();
            unsigned off = 0;
            #pragma unroll
            for (int w = 0; w < 8; ++w) off += (w < wid) ? wsum[w] : 0u;
            unsigned phi = incl + off;
            unsigned plo = phi - part;
            if (tid < (int)nb){
                if (rA >= plo && rA < phi){ s_dA = tid; s_cloA = plo; }
                if (rB >= plo && rB < phi){ s_dB = tid; s_cloB = plo; }
            }
            __syncthreads();
            unsigned dA = s_dA, dB = s_dB;
            if (dA != dB){
                unsigned mA = prefMask | (msk << shift);
                unsigned vAp = prefVal | (dA << shift);
                unsigned vBp = prefVal | (dB << shift);
                unsigned locA = 0u, locB = 0xFFFFFFFFu;
                #pragma unroll
                for (int e = 0; e < 32; ++e){
                    if ((key[e] & mA) == vAp) locA = max(locA, key[e]);
                    if ((key[e] & mA) == vBp) locB = min(locB, key[e]);
                }
                #pragma unroll
                for (int o = 32; o > 0; o >>= 1){
                    locA = max(locA, __shfl_down(locA, o));
                    locB = min(locB, __shfl_down(locB, o));
                }
                if (lane == 0){ redA[wid] = locA; redB[wid] = locB; }
                __syncthreads();
                if (tid == 0){
                    unsigned a = redA[0], b = redB[0];
                    for (int w = 1; w < 8; ++w){ a = max(a, redA[w]); b = min(b, redB[w]); }
                    s_keyA = a; s_keyB = b;
                }
                __syncthreads();
                done = true;
            } else {
                prefVal |= dA << shift;
                prefMask |= msk << shift;
                rA -= s_cloA; rB -= s_cloB;
                if (lvl == 2){
                    if (tid == 0){ s_keyA = prefVal; s_keyB = prefVal; }
                    done = true;
                }
                __syncthreads();
            }
        }
    }

    float vlo = key2f(s_keyA);
    float vhi = key2f(s_keyB);
    float idxq = 0.95f * 16383.0f;
    float frac = idxq - floorf(idxq);
    const float thr = vlo * (1.0f - frac) + vhi * frac;

    // ---- P2: mask (from registers) -> C0 bf16; hmax3 via shuffles -> Ab bf16 ----
    #pragma unroll
    for (int k = 0; k < 8; ++k){
        int i = tid + k * 512;          // float4 index 0..4095
        int c4 = i & 31;
        float4 c;
        {
            float f0 = key2f(key[4*k+0]); c.x = (f0 >= thr) ? f0 : 0.0f;
            float f1 = key2f(key[4*k+1]); c.y = (f1 >= thr) ? f1 : 0.0f;
            float f2 = key2f(key[4*k+2]); c.z = (f2 >= thr) ? f2 : 0.0f;
            float f3 = key2f(key[4*k+3]); c.w = (f3 >= thr) ? f3 : 0.0f;
        }
        ((uint2*)C0)[i] = pack2(c);
        float lf = __shfl_up(c.w, 1);
        float rt = __shfl_down(c.x, 1);
        if (c4 == 0)  lf = -FLT_MAX;
        if (c4 == 31) rt = -FLT_MAX;
        float4 a;
        a.x = fmaxf(fmaxf(lf,  c.x), c.y);
        a.y = fmaxf(fmaxf(c.x, c.y), c.z);
        a.z = fmaxf(fmaxf(c.y, c.z), c.w);
        a.w = fmaxf(fmaxf(c.z, c.w), rt);
        ((uint2*)Ab)[i] = pack2(a);
    }
    __syncthreads();

    // ---- P3: vmax3*0.99 -> a1; outp = max(c0,a1) -> global; a1 -> C0 (in place) ----
    {
        uint2* op2 = (uint2*)(outp + (size_t)bc * HW_);
        #pragma unroll
        for (int k = 0; k < 8; ++k){
            int i = tid + k * 512;
            int r = i >> 5;
            float4 m = unpack2(((uint2*)Ab)[i]);
            if (r > 0)   m = max4(m, unpack2(((uint2*)Ab)[i - 32]));
            if (r < 127) m = max4(m, unpack2(((uint2*)Ab)[i + 32]));
            float4 a1;
            a1.x = 0.99f * m.x; a1.y = 0.99f * m.y;
            a1.z = 0.99f * m.z; a1.w = 0.99f * m.w;
            float4 c0 = unpack2(((uint2*)C0)[i]);
            op2[i] = pack2(max4(c0, a1));
            ((uint2*)C0)[i] = pack2(a1);
        }
    }
    __syncthreads();

    // ---- P4: horizontal 5-tap stride-2 over a1(C0) -> H5 bf16 (Ab[0:8192]) ----
    unsigned short* H5 = Ab;
    #pragma unroll
    for (int k = 0; k < 16; ++k){
        int j = tid + k * 512;          // 0..8191
        int r = j >> 6, ci = j & 63;
        const unsigned* row32 = (const unsigned*)(C0 + r * 128);
        unsigned wm = row32[ci];                    // cols 2ci, 2ci+1
        float m = fmaxf(bf2f((unsigned short)wm),
                        __uint_as_float(wm & 0xFFFF0000u));
        if (ci > 0){
            unsigned wl = row32[ci - 1];            // cols 2ci-2, 2ci-1
            m = fmaxf(m, fmaxf(bf2f((unsigned short)wl),
                               __uint_as_float(wl & 0xFFFF0000u)));
        }
        if (ci < 63) m = fmaxf(m, bf2f(C0[r * 128 + 2*ci + 2]));
        H5[j] = f2bf(m);
    }
    __syncthreads();

    // ---- P5: vertical 5-tap stride-2 *g1 -> D f32; M = D (C0 region) ----
    float* Df = (float*)C0;
    float* Mf = Df + 4096;
    #pragma unroll
    for (int k = 0; k < 8; ++k){
        int q = tid + k * 512;          // 0..4095
        int ii = q >> 6, j = q & 63;
        int rr = 2 * ii;
        float m = fmaxf(bf2f(H5[rr * 64 + j]), bf2f(H5[(rr + 1) * 64 + j]));
        if (rr >= 1) m = fmaxf(m, bf2f(H5[(rr - 1) * 64 + j]));
        if (rr >= 2) m = fmaxf(m, bf2f(H5[(rr - 2) * 64 + j]));
        if (rr + 2 <= 127) m = fmaxf(m, bf2f(H5[(rr + 2) * 64 + j]));
        float d = g1 * m;
        Df[q] = d; Mf[q] = d;
    }
    __syncthreads();

    // ---- P6: chain x4 on 64x64 (T f32 in Ab[16KB:32KB]) ----
    float* Tf = (float*)(Ab + 8192);
    const float gs[4] = {g2, g3, g4, g5};
    for (int it = 0; it < 4; ++it){
        float g = gs[it];
        #pragma unroll
        for (int k = 0; k < 8; ++k){
            int q = tid + k * 512;
            int j = q & 63;
            float m = Df[q];
            if (j > 0)  m = fmaxf(m, Df[q - 1]);
            if (j < 63) m = fmaxf(m, Df[q + 1]);
            Tf[q] = m;
        }
        __syncthreads();
        #pragma unroll
        for (int k = 0; k < 8; ++k){
            int q = tid + k * 512;
            int r = q >> 6;
            float m = Tf[q];
            if (r > 0)  m = fmaxf(m, Tf[q - 64]);
            if (r < 63) m = fmaxf(m, Tf[q + 64]);
            float v = g * m;
            Df[q] = v;
            Mf[q] = fmaxf(Mf[q], v);
        }
        __syncthreads();
    }

    // ---- P7: write m64 bf16 ----
    {
        unsigned short* mp = m64g + (size_t)bc * 4096;
        #pragma unroll
        for (int k = 0; k < 8; ++k){
            int q = tid + k * 512;
            mp[q] = f2bf(Mf[q]);
        }
    }
}

// K3: fused  out' = max(outp, up(m64)) -> h = relu(W1 out'+b1) ->
//            R = sigmoid(W2 h + b2) -> y = x*R
// 1 px/thread, 1024 blocks (4 blocks/CU). outp/m64 read as bf16.
__global__ __launch_bounds__(256) void k3_mlp(
    const float* __restrict__ x, const unsigned short* __restrict__ outp,
    const unsigned short* __restrict__ m64,
    const float* __restrict__ w1, const float* __restrict__ b1,
    const float* __restrict__ w2, const float* __restrict__ b2,
    float* __restrict__ y)
{
    __shared__ __align__(16) float W1s[256 * 16];  // [c][m]
    __shared__ __align__(16) float W2s[256 * 16];  // [c][m]
    __shared__ float B1s[16];
    __shared__ float B2s[256];
    const int tid = threadIdx.x;
    const int blk = blockIdx.x;
    const int b = blk >> 6;
    const int t = blk & 63;

    for (int q = tid; q < 4096; q += 256){
        int c = q >> 4, m = q & 15;
        W1s[q] = w1[m * 256 + c];
        W2s[q] = w2[q];
    }
    if (tid < 16) B1s[tid] = b1[tid];
    B2s[tid] = b2[tid];
    __syncthreads();

    const int pix = t * 256 + tid;
    const int mi = (pix >> 8) * 64 + ((pix & 127) >> 1);
    const size_t base = (size_t)b * 256 * HW_;
    const size_t mbase = (size_t)b * 256 * 4096;

    float h[16];
    #pragma unroll
    for (int m = 0; m < 16; ++m) h[m] = 0.0f;

    #pragma unroll 4
    for (int c = 0; c < 256; ++c){
        float o  = bf2f(outp[base + (size_t)c * HW_ + pix]);
        float mo = bf2f(m64[mbase + (size_t)c * 4096 + mi]);
        o = fmaxf(o, mo);
        const float4* wr = (const float4*)&W1s[c * 16];
        float4 a0 = wr[0], a1 = wr[1], a2 = wr[2], a3 = wr[3];
        h[0]  = fmaf(a0.x, o, h[0]);  h[1]  = fmaf(a0.y, o, h[1]);
        h[2]  = fmaf(a0.z, o, h[2]);  h[3]  = fmaf(a0.w, o, h[3]);
        h[4]  = fmaf(a1.x, o, h[4]);  h[5]  = fmaf(a1.y, o, h[5]);
        h[6]  = fmaf(a1.z, o, h[6]);  h[7]  = fmaf(a1.w, o, h[7]);
        h[8]  = fmaf(a2.x, o, h[8]);  h[9]  = fmaf(a2.y, o, h[9]);
        h[10] = fmaf(a2.z, o, h[10]); h[11] = fmaf(a2.w, o, h[11]);
        h[12] = fmaf(a3.x, o, h[12]); h[13] = fmaf(a3.y, o, h[13]);
        h[14] = fmaf(a3.z, o, h[14]); h[15] = fmaf(a3.w, o, h[15]);
    }
    #pragma unroll
    for (int m = 0; m < 16; ++m) h[m] = fmaxf(h[m] + B1s[m], 0.0f);

    #pragma unroll 4
    for (int c = 0; c < 256; ++c){
        const float4* wr = (const float4*)&W2s[c * 16];
        float4 a0 = wr[0], a1 = wr[1], a2 = wr[2], a3 = wr[3];
        float acc = B2s[c];
        acc += a0.x * h[0]  + a0.y * h[1]  + a0.z * h[2]  + a0.w * h[3];
        acc += a1.x * h[4]  + a1.y * h[5]  + a1.z * h[6]  + a1.w * h[7];
        acc += a2.x * h[8]  + a2.y * h[9]  + a2.z * h[10] + a2.w * h[11];
        acc += a3.x * h[12] + a3.y * h[13] + a3.z * h[14] + a3.w * h[15];
        float R = 1.0f / (1.0f + __expf(-acc));
        float xv = x[base + (size_t)c * HW_ + pix];
        y[base + (size_t)c * HW_ + pix] = xv * R;
    }
}

extern "C" void kernel_launch(void* const* d_in, const int* in_sizes, int n_in,
                              void* d_out, int out_size, void* d_ws, size_t ws_size,
                              hipStream_t stream) {
    const float* x  = (const float*)d_in[0];
    const float* w1 = (const float*)d_in[1];
    const float* b1 = (const float*)d_in[2];
    const float* w2 = (const float*)d_in[3];
    const float* b2 = (const float*)d_in[4];
    float* y  = (float*)d_out;
    char* ws = (char*)d_ws;

    unsigned short* outp = (unsigned short*)ws;                 // 134 MB
    unsigned short* m64  = (unsigned short*)(ws + 134217728);   // 33.5 MB

    float g[6];
    for (int i = 0; i < 6; ++i) g[i] = (float)std::pow(0.99, (double)(1 << i));

    k1f<<<4096, 512, 0, stream>>>(x, outp, m64, g[1], g[2], g[3], g[4], g[5]);
    k3_mlp<<<1024, 256, 0, stream>>>(x, outp, m64, w1, b1, w2, b2, y);
}

// Round 8
// 314.618 us; speedup vs baseline: 2.1847x; 1.2288x over previous
//
#include <hip/hip_runtime.h>
#include <cmath>
#include <cfloat>

#define HW_ 16384

__device__ __forceinline__ unsigned f2key(float f){
    unsigned u = __float_as_uint(f);
    return u ^ ((u & 0x80000000u) ? 0xFFFFFFFFu : 0x80000000u);
}
__device__ __forceinline__ float key2f(unsigned k){
    unsigned u = (k & 0x80000000u) ? (k ^ 0x80000000u) : ~k;
    return __uint_as_float(u);
}
__device__ __forceinline__ float bf2f(unsigned short s){
    return __uint_as_float((unsigned)s << 16);
}
// packed helpers (bf16 pairs in u32; all pooled values >= 0 so u16 order == float order)
__device__ __forceinline__ unsigned pkmax(unsigned a, unsigned b){
    unsigned d;
    asm("v_pk_max_u16 %0, %1, %2" : "=v"(d) : "v"(a), "v"(b));
    return d;
}
__device__ __forceinline__ unsigned alignb(unsigned hi, unsigned lo){
    unsigned d;   // d = (hi:lo) >> 16 : (lo.e1, hi.e0) packed
    asm("v_alignbit_b32 %0, %1, %2, 16" : "=v"(d) : "v"(hi), "v"(lo));
    return d;
}
__device__ __forceinline__ unsigned cvtpk(float lo, float hi){
    unsigned d;
    asm("v_cvt_pk_bf16_f32 %0, %1, %2" : "=v"(d) : "v"(lo), "v"(hi));
    return d;
}
// 64-lane inclusive scan, no barriers
__device__ __forceinline__ unsigned wscan_incl(unsigned v, int lane){
    #pragma unroll
    for (int o = 1; o < 64; o <<= 1){
        unsigned u = __shfl_up(v, o);
        v += (lane >= o) ? u : 0u;
    }
    return v;
}

// K1f: one block per (b,c) channel, 512 threads, ~53KB LDS (3 blocks/CU).
// select (keys in regs) -> mask -> packed pool3 -> outp -> packed 5x5s2
// -> unscaled packed 64x64 chain, M fold in f32 registers -> m64.
__global__ __launch_bounds__(512, 6) void k1f(
    const float* __restrict__ x,
    unsigned short* __restrict__ outp, unsigned short* __restrict__ m64g,
    float g1, float q2, float q3, float q4, float q5, float q6)
{
    __shared__ __align__(16) unsigned short C0[16384];  // 32KB c0 packed; later U/T planes
    __shared__ __align__(16) unsigned short H5s[8192];  // 16KB H5 (128x64 bf16)
    __shared__ unsigned hist[1024];
    __shared__ unsigned wsum[8];
    __shared__ unsigned redA[8], redB[8];
    __shared__ unsigned s_dA, s_dB, s_cloA, s_cloB, s_keyA, s_keyB;

    const int tid = threadIdx.x;
    const int lane = tid & 63;
    const int wid = tid >> 6;
    const unsigned bc = blockIdx.x;
    const float4* xp4 = (const float4*)(x + (size_t)bc * HW_);

    unsigned key[32];

    // ---- P0: init hist, load x, build keys, 10-bit histogram ----
    #pragma unroll
    for (int k = 0; k < 2; ++k) hist[tid + k * 512] = 0u;
    __syncthreads();
    #pragma unroll
    for (int k = 0; k < 8; ++k){
        float4 v = xp4[tid + k * 512];
        key[4*k+0] = f2key(v.x);
        key[4*k+1] = f2key(v.y);
        key[4*k+2] = f2key(v.z);
        key[4*k+3] = f2key(v.w);
        atomicAdd(&hist[key[4*k+0] >> 22], 1u);
        atomicAdd(&hist[key[4*k+1] >> 22], 1u);
        atomicAdd(&hist[key[4*k+2] >> 22], 1u);
        atomicAdd(&hist[key[4*k+3] >> 22], 1u);
    }
    __syncthreads();

    // ---- P1: dual-rank select ----
    unsigned rA = 15563u, rB = 15564u;
    unsigned prefVal = 0u, prefMask = 0u;
    bool done = false;

    {   // level 0: 10 bits (1024 bins, 2/thread)
        unsigned part = hist[tid*2] + hist[tid*2+1];
        unsigned incl = wscan_incl(part, lane);
        if (lane == 63) wsum[wid] = incl;
        __syncthreads();
        unsigned off = 0;
        #pragma unroll
        for (int w = 0; w < 8; ++w) off += (w < wid) ? wsum[w] : 0u;
        unsigned phi = incl + off;
        unsigned plo = phi - part;
        if (rA >= plo && rA < phi){
            unsigned c = plo;
            #pragma unroll
            for (int k = 0; k < 2; ++k){
                unsigned hh = hist[tid*2+k];
                if (rA < c + hh){ s_dA = tid*2+k; s_cloA = c; break; }
                c += hh;
            }
        }
        if (rB >= plo && rB < phi){
            unsigned c = plo;
            #pragma unroll
            for (int k = 0; k < 2; ++k){
                unsigned hh = hist[tid*2+k];
                if (rB < c + hh){ s_dB = tid*2+k; s_cloB = c; break; }
                c += hh;
            }
        }
        __syncthreads();
        unsigned dA = s_dA, dB = s_dB;
        if (dA != dB){
            unsigned locA = 0u, locB = 0xFFFFFFFFu;
            #pragma unroll
            for (int e = 0; e < 32; ++e){
                unsigned d = key[e] >> 22;
                if (d == dA) locA = max(locA, key[e]);
                if (d == dB) locB = min(locB, key[e]);
            }
            #pragma unroll
            for (int o = 32; o > 0; o >>= 1){
                locA = max(locA, __shfl_down(locA, o));
                locB = min(locB, __shfl_down(locB, o));
            }
            if (lane == 0){ redA[wid] = locA; redB[wid] = locB; }
            __syncthreads();
            if (tid == 0){
                unsigned a = redA[0], b = redB[0];
                for (int w = 1; w < 8; ++w){ a = max(a, redA[w]); b = min(b, redB[w]); }
                s_keyA = a; s_keyB = b;
            }
            __syncthreads();
            done = true;
        } else {
            prefVal = dA << 22; prefMask = 0x3FFu << 22;
            rA -= s_cloA; rB -= s_cloB;
            __syncthreads();
        }
    }

    if (!done){
        const int shifts[3] = {14, 6, 0};
        const int bitsv[3]  = {8, 8, 6};
        for (int lvl = 0; lvl < 3 && !done; ++lvl){
            int shift = shifts[lvl];
            unsigned nb = 1u << bitsv[lvl];
            unsigned msk = nb - 1u;
            if (tid < (int)nb) hist[tid] = 0u;
            __syncthreads();
            #pragma unroll
            for (int e = 0; e < 32; ++e){
                if ((key[e] & prefMask) == prefVal)
                    atomicAdd(&hist[(key[e] >> shift) & msk], 1u);
            }
            __syncthreads();
            unsigned part = (tid < (int)nb) ? hist[tid] : 0u;
            unsigned incl = wscan_incl(part, lane);
            if (lane == 63) wsum[wid] = incl;
            __syncthreads();
            unsigned off = 0;
            #pragma unroll
            for (int w = 0; w < 8; ++w) off += (w < wid) ? wsum[w] : 0u;
            unsigned phi = incl + off;
            unsigned plo = phi - part;
            if (tid < (int)nb){
                if (rA >= plo && rA < phi){ s_dA = tid; s_cloA = plo; }
                if (rB >= plo && rB < phi){ s_dB = tid; s_cloB = plo; }
            }
            __syncthreads();
            unsigned dA = s_dA, dB = s_dB;
            if (dA != dB){
                unsigned mA = prefMask | (msk << shift);
                unsigned vAp = prefVal | (dA << shift);
                unsigned vBp = prefVal | (dB << shift);
                unsigned locA = 0u, locB = 0xFFFFFFFFu;
                #pragma unroll
                for (int e = 0; e < 32; ++e){
                    if ((key[e] & mA) == vAp) locA = max(locA, key[e]);
                    if ((key[e] & mA) == vBp) locB = min(locB, key[e]);
                }
                #pragma unroll
                for (int o = 32; o > 0; o >>= 1){
                    locA = max(locA, __shfl_down(locA, o));
                    locB = min(locB, __shfl_down(locB, o));
                }
                if (lane == 0){ redA[wid] = locA; redB[wid] = locB; }
                __syncthreads();
                if (tid == 0){
                    unsigned a = redA[0], b = redB[0];
                    for (int w = 1; w < 8; ++w){ a = max(a, redA[w]); b = min(b, redB[w]); }
                    s_keyA = a; s_keyB = b;
                }
                __syncthreads();
                done = true;
            } else {
                prefVal |= dA << shift;
                prefMask |= msk << shift;
                rA -= s_cloA; rB -= s_cloB;
                if (lvl == 2){
                    if (tid == 0){ s_keyA = prefVal; s_keyB = prefVal; }
                    done = true;
                }
                __syncthreads();
            }
        }
    }

    float vlo = key2f(s_keyA);
    float vhi = key2f(s_keyB);
    float idxq = 0.95f * 16383.0f;
    float frac = idxq - floorf(idxq);
    const float thr = vlo * (1.0f - frac) + vhi * frac;   // > 0 for this data

    // ---- P2: mask (regs) -> C0 packed bf16 ----
    #pragma unroll
    for (int k = 0; k < 8; ++k){
        int i = tid + k * 512;          // uint2 index 0..4095
        float f0 = key2f(key[4*k+0]); f0 = (f0 >= thr) ? f0 : 0.0f;
        float f1 = key2f(key[4*k+1]); f1 = (f1 >= thr) ? f1 : 0.0f;
        float f2 = key2f(key[4*k+2]); f2 = (f2 >= thr) ? f2 : 0.0f;
        float f3 = key2f(key[4*k+3]); f3 = (f3 >= thr) ? f3 : 0.0f;
        uint2 w; w.x = cvtpk(f0, f1); w.y = cvtpk(f2, f3);
        ((uint2*)C0)[i] = w;
    }
    __syncthreads();

    // ---- P3: per-wave row-band: hmax3 (packed, shuffled) + vmax3 carry ->
    //          p1 (unscaled pool3); outp = pkmax(c0, bf16(0.99*p1)); H5 row fused ----
    {
        const unsigned* C0w = (const unsigned*)C0;
        unsigned* outp32 = (unsigned*)(outp + (size_t)bc * HW_);
        const int wc = lane;
        const int r0 = wid * 16;

        unsigned hmA, hmB, hmC, cA, cB, cC;
        // prologue rows r0-1, r0
        {
            int r = r0 - 1;
            if (r < 0){ hmA = 0u; cA = 0u; }
            else {
                unsigned w = C0w[r*64 + wc];
                unsigned wl = __shfl_up(w, 1);
                unsigned wr = __shfl_down(w, 1);
                if (wc == 0)  wl = 0u;
                if (wc == 63) wr = 0u;
                hmA = pkmax(pkmax(alignb(w, wl), w), alignb(wr, w));
                cA = w;
            }
        }
        {
            int r = r0;
            unsigned w = C0w[r*64 + wc];
            unsigned wl = __shfl_up(w, 1);
            unsigned wr = __shfl_down(w, 1);
            if (wc == 0)  wl = 0u;
            if (wc == 63) wr = 0u;
            hmB = pkmax(pkmax(alignb(w, wl), w), alignb(wr, w));
            cB = w;
        }
        #pragma unroll
        for (int rr = 0; rr < 16; ++rr){
            int r = r0 + rr;
            {
                int rn = r + 1;
                if (rn > 127){ hmC = 0u; cC = 0u; }
                else {
                    unsigned w = C0w[rn*64 + wc];
                    unsigned wl = __shfl_up(w, 1);
                    unsigned wr = __shfl_down(w, 1);
                    if (wc == 0)  wl = 0u;
                    if (wc == 63) wr = 0u;
                    hmC = pkmax(pkmax(alignb(w, wl), w), alignb(wr, w));
                    cC = w;
                }
            }
            unsigned p1 = pkmax(pkmax(hmA, hmB), hmC);
            // outp = max(c0, 0.99*p1)
            float a0 = g1 * bf2f((unsigned short)(p1 & 0xFFFFu));
            float a1v = g1 * bf2f((unsigned short)(p1 >> 16));
            outp32[r*64 + wc] = pkmax(cB, cvtpk(a0, a1v));
            // H5[r][wc] = max(p1 cols 2wc-2..2wc+2)  (stride-2 5-tap, unscaled)
            unsigned wjm1 = __shfl_up(p1, 1);
            unsigned wjp1 = __shfl_down(p1, 1);
            if (wc == 0)  wjm1 = 0u;
            if (wc == 63) wjp1 = 0u;
            unsigned s = pkmax(wjm1, p1);
            s = pkmax(s, s >> 16);
            s = pkmax(s, wjp1 & 0xFFFFu);
            H5s[r*64 + wc] = (unsigned short)s;
            hmA = hmB; hmB = hmC; cB = cC;
        }
    }
    __syncthreads();

    // ---- P5: vertical 5-tap stride-2 over H5 -> u1 (packed, unscaled) in U;
    //          M regs = q2 * u1 ----
    unsigned* U = (unsigned*)C0;            // 8KB
    unsigned* T = ((unsigned*)C0) + 2048;   // next 8KB
    float mf[8];
    #pragma unroll
    for (int k = 0; k < 4; ++k){
        int q = tid + k * 512;              // word 0..2047
        int i = q >> 5, wj = q & 31;
        int rr = 2 * i;
        const unsigned* H5w = (const unsigned*)H5s;   // 32 words/row
        unsigned m = pkmax(H5w[rr*32 + wj], H5w[(rr+1)*32 + wj]);
        if (rr >= 1) m = pkmax(m, H5w[(rr-1)*32 + wj]);
        if (rr >= 2) m = pkmax(m, H5w[(rr-2)*32 + wj]);
        if (rr + 2 <= 127) m = pkmax(m, H5w[(rr+2)*32 + wj]);
        U[q] = m;
        mf[2*k]   = q2 * bf2f((unsigned short)(m & 0xFFFFu));
        mf[2*k+1] = q2 * bf2f((unsigned short)(m >> 16));
    }
    __syncthreads();

    // ---- P6: 4x unscaled pool3 on 64x64 packed; fold gs[it]*u into M regs ----
    const float gs[4] = {q3, q4, q5, q6};
    #pragma unroll
    for (int it = 0; it < 4; ++it){
        #pragma unroll
        for (int k = 0; k < 4; ++k){
            int q = tid + k * 512;
            unsigned w = U[q];
            unsigned wl = __shfl_up(w, 1);
            unsigned wr = __shfl_down(w, 1);
            if ((q & 31) == 0)  wl = 0u;
            if ((q & 31) == 31) wr = 0u;
            T[q] = pkmax(pkmax(alignb(w, wl), w), alignb(wr, w));
        }
        __syncthreads();
        #pragma unroll
        for (int k = 0; k < 4; ++k){
            int q = tid + k * 512;
            int r = q >> 5;
            unsigned w = T[q];
            if (r > 0)  w = pkmax(w, T[q - 32]);
            if (r < 63) w = pkmax(w, T[q + 32]);
            U[q] = w;
            mf[2*k]   = fmaxf(mf[2*k],   gs[it] * bf2f((unsigned short)(w & 0xFFFFu)));
            mf[2*k+1] = fmaxf(mf[2*k+1], gs[it] * bf2f((unsigned short)(w >> 16)));
        }
        __syncthreads();
    }

    // ---- P7: write m64 from M regs ----
    {
        unsigned* mp = (unsigned*)(m64g + (size_t)bc * 4096);
        #pragma unroll
        for (int k = 0; k < 4; ++k){
            int q = tid + k * 512;
            mp[q] = cvtpk(mf[2*k], mf[2*k+1]);
        }
    }
}

// K3: fused  out' = max(outp, up(m64)) -> h = relu(W1 out'+b1) ->
//            R = sigmoid(W2 h + b2) -> y = x*R
__global__ __launch_bounds__(256) void k3_mlp(
    const float* __restrict__ x, const unsigned short* __restrict__ outp,
    const unsigned short* __restrict__ m64,
    const float* __restrict__ w1, const float* __restrict__ b1,
    const float* __restrict__ w2, const float* __restrict__ b2,
    float* __restrict__ y)
{
    __shared__ __align__(16) float W1s[256 * 16];  // [c][m]
    __shared__ __align__(16) float W2s[256 * 16];  // [c][m]
    __shared__ float B1s[16];
    __shared__ float B2s[256];
    const int tid = threadIdx.x;
    const int blk = blockIdx.x;
    const int b = blk >> 6;
    const int t = blk & 63;

    for (int q = tid; q < 4096; q += 256){
        int c = q >> 4, m = q & 15;
        W1s[q] = w1[m * 256 + c];
        W2s[q] = w2[q];
    }
    if (tid < 16) B1s[tid] = b1[tid];
    B2s[tid] = b2[tid];
    __syncthreads();

    const int pix = t * 256 + tid;
    const int mi = (pix >> 8) * 64 + ((pix & 127) >> 1);
    const size_t base = (size_t)b * 256 * HW_;
    const size_t mbase = (size_t)b * 256 * 4096;

    float h[16];
    #pragma unroll
    for (int m = 0; m < 16; ++m) h[m] = 0.0f;

    #pragma unroll 4
    for (int c = 0; c < 256; ++c){
        float o  = bf2f(outp[base + (size_t)c * HW_ + pix]);
        float mo = bf2f(m64[mbase + (size_t)c * 4096 + mi]);
        o = fmaxf(o, mo);
        const float4* wr = (const float4*)&W1s[c * 16];
        float4 a0 = wr[0], a1 = wr[1], a2 = wr[2], a3 = wr[3];
        h[0]  = fmaf(a0.x, o, h[0]);  h[1]  = fmaf(a0.y, o, h[1]);
        h[2]  = fmaf(a0.z, o, h[2]);  h[3]  = fmaf(a0.w, o, h[3]);
        h[4]  = fmaf(a1.x, o, h[4]);  h[5]  = fmaf(a1.y, o, h[5]);
        h[6]  = fmaf(a1.z, o, h[6]);  h[7]  = fmaf(a1.w, o, h[7]);
        h[8]  = fmaf(a2.x, o, h[8]);  h[9]  = fmaf(a2.y, o, h[9]);
        h[10] = fmaf(a2.z, o, h[10]); h[11] = fmaf(a2.w, o, h[11]);
        h[12] = fmaf(a3.x, o, h[12]); h[13] = fmaf(a3.y, o, h[13]);
        h[14] = fmaf(a3.z, o, h[14]); h[15] = fmaf(a3.w, o, h[15]);
    }
    #pragma unroll
    for (int m = 0; m < 16; ++m) h[m] = fmaxf(h[m] + B1s[m], 0.0f);

    #pragma unroll 4
    for (int c = 0; c < 256; ++c){
        const float4* wr = (const float4*)&W2s[c * 16];
        float4 a0 = wr[0], a1 = wr[1], a2 = wr[2], a3 = wr[3];
        float acc = B2s[c];
        acc += a0.x * h[0]  + a0.y * h[1]  + a0.z * h[2]  + a0.w * h[3];
        acc += a1.x * h[4]  + a1.y * h[5]  + a1.z * h[6]  + a1.w * h[7];
        acc += a2.x * h[8]  + a2.y * h[9]  + a2.z * h[10] + a2.w * h[11];
        acc += a3.x * h[12] + a3.y * h[13] + a3.z * h[14] + a3.w * h[15];
        float R = 1.0f / (1.0f + __expf(-acc));
        float xv = x[base + (size_t)c * HW_ + pix];
        y[base + (size_t)c * HW_ + pix] = xv * R;
    }
}

extern "C" void kernel_launch(void* const* d_in, const int* in_sizes, int n_in,
                              void* d_out, int out_size, void* d_ws, size_t ws_size,
                              hipStream_t stream) {
    const float* x  = (const float*)d_in[0];
    const float* w1 = (const float*)d_in[1];
    const float* b1 = (const float*)d_in[2];
    const float* w2 = (const float*)d_in[3];
    const float* b2 = (const float*)d_in[4];
    float* y  = (float*)d_out;
    char* ws = (char*)d_ws;

    unsigned short* outp = (unsigned short*)ws;                 // 134 MB
    unsigned short* m64  = (unsigned short*)(ws + 134217728);   // 33.5 MB

    // composed scales: feat_i = 0.99^(2^i) * pool(feat_{i-1}); pools are
    // positively homogeneous so stage k's field = 0.99^(2^{k+1}-1) * unscaled pool^k
    float g1 = 0.99f;
    float q2 = (float)std::pow(0.99, 3.0);
    float q3 = (float)std::pow(0.99, 7.0);
    float q4 = (float)std::pow(0.99, 15.0);
    float q5 = (float)std::pow(0.99, 31.0);
    float q6 = (float)std::pow(0.99, 63.0);

    k1f<<<4096, 512, 0, stream>>>(x, outp, m64, g1, q2, q3, q4, q5, q6);
    k3_mlp<<<1024, 256, 0, stream>>>(x, outp, m64, w1, b1, w2, b2, y);
}